// Round 12
// baseline (182.350 us; speedup 1.0000x reference)
//
#include <hip/hip_runtime.h>
#include <math.h>

// B=2, LS=2048, G=32, KNN=16, DIM=256, PE=32, H=8, DH=32, INNER=256, FF=1024
#define LS 2048
#define NG 32
#define ROWS_B 2080
#define DIM 256
#define PE 32
#define NH 8
#define DH 32
#define NCTX 49
#define SCALE 0.17677669529663687f  // 1/sqrt(32)
#define QSTR 1536                   // QKV2 row stride: q|k|v|qw|gs

typedef __attribute__((ext_vector_type(8))) short short8;
typedef __attribute__((ext_vector_type(4))) float f32x4;
typedef __attribute__((ext_vector_type(4))) unsigned short us4;

__device__ __forceinline__ unsigned short f2bf(float x)
{
    unsigned int u = __float_as_uint(x);
    unsigned int r = (u + 0x7fffu + ((u >> 16) & 1u)) >> 16;
    return (unsigned short)r;
}
__device__ __forceinline__ float bf2f(unsigned short v)
{
    return __uint_as_float((unsigned int)v << 16);
}
__device__ __forceinline__ float4 bf2f4(us4 v)
{
    return (float4){ bf2f(v.x), bf2f(v.y), bf2f(v.z), bf2f(v.w) };
}
__device__ __forceinline__ float dot4(float4 a, float4 b)
{
    return a.x * b.x + a.y * b.y + a.z * b.z + a.w * b.w;
}
__device__ __forceinline__ float gelu_f(float x)
{
    float x3 = x * x * x;
    return 0.5f * x * (1.0f + tanhf(0.7978845608028654f * (x + 0.044715f * x3)));
}

struct WEnt { const float* src; unsigned short* dst; int K; int N; int t0; };
struct WTab { WEnt e[9]; };

// ---------------- merged prep: wspecial (512) + wconv (224) + ln1/ln3 (4160) ----------------
__global__ __launch_bounds__(256) void wprep_k(
    WTab tab,
    const float* __restrict__ sa_wq, const float* __restrict__ sa_wk,
    const float* __restrict__ sa_wv, const float* __restrict__ sa_wo,
    unsigned short* __restrict__ wt_qkvw, unsigned short* __restrict__ wt_wo2,
    const float* __restrict__ latents,
    const float* __restrict__ g1, const float* __restrict__ b1,
    const float* __restrict__ g3, const float* __restrict__ b3,
    float* __restrict__ X, float* __restrict__ GQ)
{
    __shared__ unsigned short tile[64][72];
    __shared__ float red[8];
    int blk = blockIdx.x, t = threadIdx.x;
    if (blk < 512) {
        const float* wkpe = sa_wk + 256 * 256;
        const float* wvpe = sa_wv + 256 * 256;
        if (blk < 256) {
            int j = blk, h = j >> 5, p = j & 31;
            const float* wq = sa_wq + (size_t)t * 256 + h * 32;
            const float* wk = wkpe + (size_t)p * 256 + h * 32;
            float acc = 0.0f;
            #pragma unroll
            for (int dd = 0; dd < 32; ++dd) acc += wq[dd] * wk[dd];
            wt_qkvw[(size_t)(768 + j) * 256 + t] = f2bf(acc);
        } else {
            int n = blk - 256;
            #pragma unroll
            for (int kk = 0; kk < 2; ++kk) {
                int k = t + kk * 256;
                float v;
                if (k < 256) v = sa_wo[(size_t)k * 256 + n];
                else {
                    int j = k - 256, h = j >> 5, p = j & 31;
                    float a = 0.0f;
                    #pragma unroll
                    for (int dd = 0; dd < 32; ++dd)
                        a += wvpe[(size_t)p * 256 + h * 32 + dd] * sa_wo[(size_t)(h * 32 + dd) * 256 + n];
                    v = a;
                }
                wt_wo2[(size_t)n * 512 + k] = f2bf(v);
            }
        }
    } else if (blk < 736) {
        int local0 = blk - 512;
        int i = 0;
        #pragma unroll
        for (int j = 1; j < 9; ++j) if (local0 >= tab.e[j].t0) i = j;
        const float* W = tab.e[i].src;
        unsigned short* Wt = tab.e[i].dst;
        int K = tab.e[i].K, N = tab.e[i].N;
        int local = local0 - tab.e[i].t0;
        int nb = N >> 6;
        int n0 = (local % nb) * 64, k0 = (local / nb) * 64;
        #pragma unroll
        for (int r = 0; r < 4; ++r) {
            int k = r * 16 + (t >> 4);
            int n = (t & 15) * 4;
            float4 wv = *(const float4*)(W + (size_t)(k0 + k) * N + n0 + n);
            tile[k][n + 0] = f2bf(wv.x);
            tile[k][n + 1] = f2bf(wv.y);
            tile[k][n + 2] = f2bf(wv.z);
            tile[k][n + 3] = f2bf(wv.w);
        }
        __syncthreads();
        #pragma unroll
        for (int r = 0; r < 4; ++r) {
            int n = r * 16 + (t >> 4);
            int k = (t & 15) * 4;
            us4 o;
            o.x = tile[k + 0][n];
            o.y = tile[k + 1][n];
            o.z = tile[k + 2][n];
            o.w = tile[k + 3][n];
            *(us4*)(Wt + (size_t)(n0 + n) * K + k0 + k) = o;
        }
    } else {
        int blk2 = blk - 736;
        const float* gam; const float* bet; size_t ip; float* op;
        if (blk2 < 4096) {
            int b = blk2 >> 11;
            ip = ((size_t)b * ROWS_B + (blk2 & 2047)) * DIM + t;
            op = X + (size_t)blk2 * DIM + t;
            gam = g1; bet = b1;
        } else {
            int r2 = blk2 - 4096;
            int b = r2 >> 5;
            ip = ((size_t)b * ROWS_B + LS + (r2 & 31)) * DIM + t;
            op = GQ + (size_t)r2 * DIM + t;
            gam = g3; bet = b3;
        }
        float v = latents[ip];
        float a = v, b2 = v * v;
        #pragma unroll
        for (int m = 32; m >= 1; m >>= 1) { a += __shfl_xor(a, m); b2 += __shfl_xor(b2, m); }
        if ((t & 63) == 0) { red[t >> 6] = a; red[4 + (t >> 6)] = b2; }
        __syncthreads();
        float mean = (red[0] + red[1] + red[2] + red[3]) * (1.0f / 256.0f);
        float var  = (red[4] + red[5] + red[6] + red[7]) * (1.0f / 256.0f) - mean * mean;
        *op = (v - mean) * rsqrtf(var + 1e-5f) * gam[t] + bet[t];
    }
}

// ---------------- plain LN (ln2) ----------------
__global__ __launch_bounds__(256) void ln_rows_k(
    const float* __restrict__ in, const float* __restrict__ gam,
    const float* __restrict__ bet, float* __restrict__ out)
{
    __shared__ float red[8];
    int r = blockIdx.x, t = threadIdx.x;
    int b = r >> 11;
    size_t ip = ((size_t)b * ROWS_B + (r & 2047)) * DIM + t;
    float v = in[ip];
    float a = v, b2 = v * v;
    #pragma unroll
    for (int m = 32; m >= 1; m >>= 1) { a += __shfl_xor(a, m); b2 += __shfl_xor(b2, m); }
    if ((t & 63) == 0) { red[t >> 6] = a; red[4 + (t >> 6)] = b2; }
    __syncthreads();
    float mean = (red[0] + red[1] + red[2] + red[3]) * (1.0f / 256.0f);
    float var  = (red[4] + red[5] + red[6] + red[7]) * (1.0f / 256.0f) - mean * mean;
    out[(size_t)r * DIM + t] = (v - mean) * rsqrtf(var + 1e-5f) * gam[t] + bet[t];
}

// ---------------- wgs: glob-score fold weights (stored contiguously after wt_qkvw) ----
__global__ __launch_bounds__(256) void wgs_k(
    const unsigned short* __restrict__ wtq, const unsigned short* __restrict__ kvglb,
    unsigned short* __restrict__ wgs)
{
    int n = blockIdx.x, k = threadIdx.x;
    int h = n & 7, cg = n >> 3;
    float acc = 0.0f;
    #pragma unroll
    for (int dd = 0; dd < 32; ++dd)
        acc += bf2f(wtq[(size_t)(h * 32 + dd) * 256 + k]) * bf2f(kvglb[(size_t)cg * 512 + h * 32 + dd]);
    wgs[(size_t)n * 256 + k] = f2bf(acc);
}

// ---------------- bf16 MFMA GEMM, 64x64 tile (small-M cases) ----------------
template<int BIAS, int DOGELU, int RES, int ABF16, int CBF16>
__global__ __launch_bounds__(256) void mgemm_k(
    const void* __restrict__ Av, const unsigned short* __restrict__ Bt,
    const float* __restrict__ bias, const float* __restrict__ Res,
    void* __restrict__ Cv, int M, int N, int K, int bstr,
    int arpb, int absr, int aoff, int crpb, int cbsr, int coff)
{
    __shared__ unsigned short Asl[64][64];
    __shared__ unsigned short Bsl[64][64];
    int t = threadIdx.x;
    int col0 = blockIdx.x * 64, row0 = blockIdx.y * 64;
    int lane = t & 63, w = t >> 6;
    int wr = w >> 1, wc = w & 1;
    int lrow = lane & 15, lk = lane >> 4;

    int srow = t >> 4;
    int scol = (t & 15) << 2;
    int sslot = (t & 15) >> 1;
    int shalf = (t & 15) & 1;

    f32x4 acc[2][2];
    #pragma unroll
    for (int m = 0; m < 2; ++m)
        #pragma unroll
        for (int n = 0; n < 2; ++n)
            acc[m][n] = (f32x4){0.f, 0.f, 0.f, 0.f};

    for (int kk = 0; kk < K; kk += 64) {
        #pragma unroll
        for (int r = 0; r < 4; ++r) {
            int row = r * 16 + srow;
            int ar = row0 + row;
            size_t ab = ((size_t)(ar / arpb) * absr + aoff + (ar % arpb)) * (size_t)K + kk + scol;
            us4 ap;
            if (ABF16) {
                ap = *(const us4*)((const unsigned short*)Av + ab);
            } else {
                float4 av = *(const float4*)((const float*)Av + ab);
                ap.x = f2bf(av.x); ap.y = f2bf(av.y); ap.z = f2bf(av.z); ap.w = f2bf(av.w);
            }
            *(us4*)&Asl[row][((sslot ^ (row & 7)) << 3) + (shalf << 2)] = ap;
            us4 bv = *(const us4*)(Bt + (size_t)(col0 + row) * bstr + kk + scol);
            *(us4*)&Bsl[row][((sslot ^ (row & 7)) << 3) + (shalf << 2)] = bv;
        }
        __syncthreads();
        #pragma unroll
        for (int k2 = 0; k2 < 2; ++k2) {
            short8 af[2], bfr[2];
            #pragma unroll
            for (int m = 0; m < 2; ++m) {
                int rowA = wr * 32 + m * 16 + lrow;
                af[m] = *(short8*)&Asl[rowA][((k2 * 4 + lk) ^ (rowA & 7)) << 3];
                int rowB = wc * 32 + m * 16 + lrow;
                bfr[m] = *(short8*)&Bsl[rowB][((k2 * 4 + lk) ^ (rowB & 7)) << 3];
            }
            #pragma unroll
            for (int m = 0; m < 2; ++m)
                #pragma unroll
                for (int n = 0; n < 2; ++n)
                    acc[m][n] = __builtin_amdgcn_mfma_f32_16x16x32_bf16(af[m], bfr[n], acc[m][n], 0, 0, 0);
        }
        __syncthreads();
    }
    #pragma unroll
    for (int m = 0; m < 2; ++m) {
        #pragma unroll
        for (int n = 0; n < 2; ++n) {
            int col = col0 + wc * 32 + n * 16 + lrow;
            #pragma unroll
            for (int j = 0; j < 4; ++j) {
                int r = row0 + wr * 32 + m * 16 + lk * 4 + j;
                size_t cp = ((size_t)(r / crpb) * cbsr + coff + (r % crpb)) * (size_t)N + col;
                float o = acc[m][n][j];
                if (BIAS)   o += bias[col];
                if (DOGELU) o = gelu_f(o);
                if (RES)    o += Res[cp];
                if (CBF16) ((unsigned short*)Cv)[cp] = f2bf(o);
                else       ((float*)Cv)[cp] = o;
            }
        }
    }
}

// ---------------- bf16 MFMA GEMM, 128x64 tile (M=4096 cases) ----------------
// 4 waves in 2x2 over (128,64): wave = 64 rows x 32 cols, acc[4][2].
// Per K-step: 16 MFMA vs 12 ds_read_b128 (2x FLOP/block vs 64-tile).
template<int BIAS, int DOGELU, int RES, int ABF16, int CBF16>
__global__ __launch_bounds__(256) void mgemm128_k(
    const void* __restrict__ Av, const unsigned short* __restrict__ Bt,
    const float* __restrict__ bias, const float* __restrict__ Res,
    void* __restrict__ Cv, int M, int N, int K, int bstr,
    int arpb, int absr, int aoff, int crpb, int cbsr, int coff)
{
    __shared__ unsigned short Asl[128][64];
    __shared__ unsigned short Bsl[64][64];
    int t = threadIdx.x;
    int col0 = blockIdx.x * 64, row0 = blockIdx.y * 128;
    int lane = t & 63, w = t >> 6;
    int wr = w >> 1, wc = w & 1;
    int lrow = lane & 15, lk = lane >> 4;

    int srow = t >> 4;
    int scol = (t & 15) << 2;
    int sslot = (t & 15) >> 1;
    int shalf = (t & 15) & 1;

    f32x4 acc[4][2];
    #pragma unroll
    for (int m = 0; m < 4; ++m)
        #pragma unroll
        for (int n = 0; n < 2; ++n)
            acc[m][n] = (f32x4){0.f, 0.f, 0.f, 0.f};

    for (int kk = 0; kk < K; kk += 64) {
        #pragma unroll
        for (int r = 0; r < 8; ++r) {
            int row = r * 16 + srow;
            int ar = row0 + row;
            size_t ab = ((size_t)(ar / arpb) * absr + aoff + (ar % arpb)) * (size_t)K + kk + scol;
            us4 ap;
            if (ABF16) {
                ap = *(const us4*)((const unsigned short*)Av + ab);
            } else {
                float4 av = *(const float4*)((const float*)Av + ab);
                ap.x = f2bf(av.x); ap.y = f2bf(av.y); ap.z = f2bf(av.z); ap.w = f2bf(av.w);
            }
            *(us4*)&Asl[row][((sslot ^ (row & 7)) << 3) + (shalf << 2)] = ap;
        }
        #pragma unroll
        for (int r = 0; r < 4; ++r) {
            int row = r * 16 + srow;
            us4 bv = *(const us4*)(Bt + (size_t)(col0 + row) * bstr + kk + scol);
            *(us4*)&Bsl[row][((sslot ^ (row & 7)) << 3) + (shalf << 2)] = bv;
        }
        __syncthreads();
        #pragma unroll
        for (int k2 = 0; k2 < 2; ++k2) {
            short8 af[4], bfr[2];
            #pragma unroll
            for (int m = 0; m < 4; ++m) {
                int rowA = wr * 64 + m * 16 + lrow;
                af[m] = *(short8*)&Asl[rowA][((k2 * 4 + lk) ^ (rowA & 7)) << 3];
            }
            #pragma unroll
            for (int n = 0; n < 2; ++n) {
                int rowB = wc * 32 + n * 16 + lrow;
                bfr[n] = *(short8*)&Bsl[rowB][((k2 * 4 + lk) ^ (rowB & 7)) << 3];
            }
            #pragma unroll
            for (int m = 0; m < 4; ++m)
                #pragma unroll
                for (int n = 0; n < 2; ++n)
                    acc[m][n] = __builtin_amdgcn_mfma_f32_16x16x32_bf16(af[m], bfr[n], acc[m][n], 0, 0, 0);
        }
        __syncthreads();
    }
    #pragma unroll
    for (int m = 0; m < 4; ++m) {
        #pragma unroll
        for (int n = 0; n < 2; ++n) {
            int col = col0 + wc * 32 + n * 16 + lrow;
            #pragma unroll
            for (int j = 0; j < 4; ++j) {
                int r = row0 + wr * 64 + m * 16 + lk * 4 + j;
                size_t cp = ((size_t)(r / crpb) * cbsr + coff + (r % crpb)) * (size_t)N + col;
                float o = acc[m][n][j];
                if (BIAS)   o += bias[col];
                if (DOGELU) o = gelu_f(o);
                if (RES)    o += Res[cp];
                if (CBF16) ((unsigned short*)Cv)[cp] = f2bf(o);
                else       ((float*)Cv)[cp] = o;
            }
        }
    }
}

// ---------------- fused spatial attention (QKV2 stride 1536, GS inline at +1024) ----------------
__global__ __launch_bounds__(256) void attn_sp_k(
    const unsigned short* __restrict__ QKV, const unsigned short* __restrict__ KVGLb,
    const int* __restrict__ idx, const float* __restrict__ rpe,
    const float* __restrict__ srpe, const float* __restrict__ dist,
    const float* __restrict__ lsig, const float* __restrict__ gbias,
    unsigned short* __restrict__ ORb)
{
    __shared__ float s_rpe[17 * 32];
    __shared__ float s_sc[NCTX * 8];
    __shared__ float s_red[32 * 64];
    __shared__ float s_d[16];
    __shared__ int   s_row[17];
    int t = threadIdx.x;
    int r = blockIdx.x;
    int b = r >> 11;
    int w = t >> 6, lane = t & 63;
    int h = lane >> 3, dg = lane & 7;

    if (t < 32) s_rpe[t] = srpe[(size_t)r * 32 + t];
    for (int i = t; i < 512; i += 256) s_rpe[32 + i] = rpe[(size_t)r * 512 + i];
    if (t < 16) {
        s_row[t + 1] = (b << 11) + idx[r * 16 + t];
        s_d[t] = dist[(size_t)r * 16 + t];
    }
    if (t == 16) s_row[0] = r;

    size_t qb = (size_t)r * QSTR + lane * 4;
    float4 q4  = bf2f4(*(const us4*)(QKV + qb));
    float4 qw4 = bf2f4(*(const us4*)(QKV + qb + 768));
    float inv2s = 1.0f / (2.0f * __expf(2.0f * lsig[h]));
    float gb = gbias[0];
    __syncthreads();

    us4 kreg[5];
    #pragma unroll
    for (int i = 0; i < 5; ++i) {
        int c = w + 4 * i;
        if (c < 17) kreg[i] = *(const us4*)(QKV + (size_t)s_row[c] * QSTR + 256 + lane * 4);
    }
    float sc_loc[5];
    #pragma unroll
    for (int i = 0; i < 5; ++i) {
        int c = w + 4 * i;
        if (c < 17) {
            float4 k4 = bf2f4(kreg[i]);
            float4 rv4 = *(const float4*)&s_rpe[c * 32 + dg * 4];
            float part = dot4(q4, k4) + dot4(rv4, qw4);
            part += __shfl_xor(part, 1);
            part += __shfl_xor(part, 2);
            part += __shfl_xor(part, 4);
            float bia = (c == 0) ? 0.0f : -s_d[c - 1] * s_d[c - 1] * inv2s;
            float sval = part * SCALE + bia;
            if (dg == 0) s_sc[c * 8 + h] = sval;
            sc_loc[i] = sval;
        }
    }
    float sc_glob[8];
    #pragma unroll
    for (int i = 0; i < 8; ++i) {
        int gi = w + 4 * i;
        float sval = bf2f(QKV[(size_t)r * QSTR + 1024 + (((size_t)b * 32 + gi) << 3) + h]) * SCALE + gb;
        if (dg == 0) s_sc[(17 + gi) * 8 + h] = sval;
        sc_glob[i] = sval;
    }
    __syncthreads();

    float vals[7];
    float lm = -3.0e38f;
    #pragma unroll
    for (int i = 0; i < 7; ++i) {
        int cc = dg + 8 * i;
        if (cc < NCTX) { float v = s_sc[cc * 8 + h]; vals[i] = v; lm = fmaxf(lm, v); }
    }
    lm = fmaxf(lm, __shfl_xor(lm, 1));
    lm = fmaxf(lm, __shfl_xor(lm, 2));
    lm = fmaxf(lm, __shfl_xor(lm, 4));
    float ls = 0.0f;
    #pragma unroll
    for (int i = 0; i < 7; ++i) {
        int cc = dg + 8 * i;
        if (cc < NCTX) ls += __expf(vals[i] - lm);
    }
    ls += __shfl_xor(ls, 1);
    ls += __shfl_xor(ls, 2);
    ls += __shfl_xor(ls, 4);
    float inv = 1.0f / ls;

    us4 vreg[5];
    #pragma unroll
    for (int i = 0; i < 5; ++i) {
        int c = w + 4 * i;
        if (c < 17) vreg[i] = *(const us4*)(QKV + (size_t)s_row[c] * QSTR + 512 + lane * 4);
    }
    float4 acc4 = (float4){0, 0, 0, 0}, racc4 = (float4){0, 0, 0, 0};
    #pragma unroll
    for (int i = 0; i < 5; ++i) {
        int c = w + 4 * i;
        if (c < 17) {
            float p = __expf(sc_loc[i] - lm);
            float4 v4 = bf2f4(vreg[i]);
            float4 rv4 = *(const float4*)&s_rpe[c * 32 + dg * 4];
            racc4.x += p * rv4.x; racc4.y += p * rv4.y;
            racc4.z += p * rv4.z; racc4.w += p * rv4.w;
            acc4.x += p * v4.x; acc4.y += p * v4.y;
            acc4.z += p * v4.z; acc4.w += p * v4.w;
        }
    }
    #pragma unroll
    for (int i = 0; i < 8; ++i) {
        int gi = w + 4 * i;
        float p = __expf(sc_glob[i] - lm);
        float4 v4 = bf2f4(*(const us4*)(KVGLb + ((size_t)(b * NG + gi)) * 512 + 256 + lane * 4));
        acc4.x += p * v4.x; acc4.y += p * v4.y;
        acc4.z += p * v4.z; acc4.w += p * v4.w;
    }

    s_red[(w * 8 + 0) * 64 + lane] = acc4.x;
    s_red[(w * 8 + 1) * 64 + lane] = acc4.y;
    s_red[(w * 8 + 2) * 64 + lane] = acc4.z;
    s_red[(w * 8 + 3) * 64 + lane] = acc4.w;
    s_red[(w * 8 + 4) * 64 + lane] = racc4.x;
    s_red[(w * 8 + 5) * 64 + lane] = racc4.y;
    s_red[(w * 8 + 6) * 64 + lane] = racc4.z;
    s_red[(w * 8 + 7) * 64 + lane] = racc4.w;
    __syncthreads();
    {
        int j = w;
        float a = 0.0f, rr = 0.0f;
        #pragma unroll
        for (int ww = 0; ww < 4; ++ww) {
            a  += s_red[(ww * 8 + j) * 64 + lane];
            rr += s_red[(ww * 8 + 4 + j) * 64 + lane];
        }
        int e = h * 32 + dg * 4 + j;
        ORb[(size_t)r * 512 + e]       = f2bf(a * inv);
        ORb[(size_t)r * 512 + 256 + e] = f2bf(rr * inv);
    }
}

// ---------------- global attention: scores via MFMA ----------------
__global__ __launch_bounds__(256) void ga_scores_k(
    const unsigned short* __restrict__ GKVQ, const unsigned short* __restrict__ KVG,
    float* __restrict__ A2)
{
    int t = threadIdx.x;
    int bh = blockIdx.x;
    int b = bh >> 3, h = bh & 7;
    int w = t >> 6, lane = t & 63;
    int ct = blockIdx.y * 4 + w;
    if (ct >= 130) return;
    int lr = lane & 15, lq = lane >> 4;

    short8 aq0 = *(const short8*)(GKVQ + ((size_t)(b * 32 + lr)) * 768 + 512 + h * 32 + lq * 8);
    short8 aq1 = *(const short8*)(GKVQ + ((size_t)(b * 32 + 16 + lr)) * 768 + 512 + h * 32 + lq * 8);
    int c = ct * 16 + lr;
    const unsigned short* kr = (c < LS)
        ? KVG + ((size_t)(b * LS + c)) * 512 + h * 32 + lq * 8
        : GKVQ + ((size_t)(b * NG + (c - LS))) * 768 + h * 32 + lq * 8;
    short8 bk = *(const short8*)kr;

    f32x4 acc0 = (f32x4){0, 0, 0, 0}, acc1 = (f32x4){0, 0, 0, 0};
    acc0 = __builtin_amdgcn_mfma_f32_16x16x32_bf16(aq0, bk, acc0, 0, 0, 0);
    acc1 = __builtin_amdgcn_mfma_f32_16x16x32_bf16(aq1, bk, acc1, 0, 0, 0);

    float* arow = A2 + ((size_t)(b * NH + h) * NG) * ROWS_B + ct * 16 + lr;
    #pragma unroll
    for (int j = 0; j < 4; ++j) {
        arow[(size_t)(lq * 4 + j) * ROWS_B]        = acc0[j] * SCALE;
        arow[(size_t)(16 + lq * 4 + j) * ROWS_B]   = acc1[j] * SCALE;
    }
}

// ---------------- global attention: row softmax over 2080 ----------------
__global__ __launch_bounds__(256) void ga_softmax_k(float* __restrict__ A2)
{
    __shared__ float red[8];
    int t = threadIdx.x;
    float* row = A2 + (size_t)blockIdx.x * ROWS_B;
    float lm = -1e30f;
    for (int i = t; i < ROWS_B; i += 256) lm = fmaxf(lm, row[i]);
    #pragma unroll
    for (int m = 32; m >= 1; m >>= 1) lm = fmaxf(lm, __shfl_xor(lm, m));
    if ((t & 63) == 0) red[t >> 6] = lm;
    __syncthreads();
    float M = fmaxf(fmaxf(red[0], red[1]), fmaxf(red[2], red[3]));
    float ls = 0.0f;
    for (int i = t; i < ROWS_B; i += 256) {
        float e = __expf(row[i] - M);
        row[i] = e;
        ls += e;
    }
    #pragma unroll
    for (int m = 32; m >= 1; m >>= 1) ls += __shfl_xor(ls, m);
    if ((t & 63) == 0) red[4 + (t >> 6)] = ls;
    __syncthreads();
    float inv = 1.0f / (red[4] + red[5] + red[6] + red[7]);
    for (int i = t; i < ROWS_B; i += 256) row[i] *= inv;
}

// ---------------- global attention: weighted V (32-way split-K, bf16) ----------------
__global__ __launch_bounds__(256) void ga_wv_k(
    const float* __restrict__ A2, const unsigned short* __restrict__ GKVQ,
    const unsigned short* __restrict__ KVG, float* __restrict__ OGP)
{
    __shared__ float s_acc[8][256];
    int t = threadIdx.x;
    int bg = blockIdx.x;       // b*32+g
    int s = blockIdx.y;        // 0..31
    int b = bg >> 5, g = bg & 31;
    int tt = t & 31, sub = t >> 5;
    int h = tt >> 2;
    const float* w = A2 + ((size_t)(b * NH + h) * NG + g) * ROWS_B;
    int c0 = s * 65, cend = c0 + 65;
    float acc[8] = {};
    for (int c = c0 + sub; c < cend; c += 8) {
        float p = w[c];
        const unsigned short* vr = (c < LS)
            ? KVG + ((size_t)(b * LS + c)) * 512 + 256 + tt * 8
            : GKVQ + ((size_t)(b * NG + (c - LS))) * 768 + 256 + tt * 8;
        us4 v0 = *(const us4*)vr;
        us4 v1 = *(const us4*)(vr + 4);
        acc[0] += p * bf2f(v0.x); acc[1] += p * bf2f(v0.y);
        acc[2] += p * bf2f(v0.z); acc[3] += p * bf2f(v0.w);
        acc[4] += p * bf2f(v1.x); acc[5] += p * bf2f(v1.y);
        acc[6] += p * bf2f(v1.z); acc[7] += p * bf2f(v1.w);
    }
    #pragma unroll
    for (int j = 0; j < 8; ++j) s_acc[sub][tt * 8 + j] = acc[j];
    __syncthreads();
    float o = 0.0f;
    #pragma unroll
    for (int ss = 0; ss < 8; ++ss) o += s_acc[ss][t];
    OGP[((size_t)bg * 32 + s) * 256 + t] = o;
}

// ---------------- glob tail, 4 blocks per row ----------------
__global__ __launch_bounds__(1024) void glob_tail_k(
    const float* __restrict__ OGP, const float* __restrict__ latents,
    const float* __restrict__ ga_wo, const float* __restrict__ ga_bo,
    const float* __restrict__ ln4g, const float* __restrict__ ln4b,
    const float* __restrict__ w1, const float* __restrict__ b1,
    const float* __restrict__ w2, const float* __restrict__ b2,
    float* __restrict__ GTP)
{
    __shared__ float s_part[4][256];
    __shared__ float s_og[256];
    __shared__ float s_y[256];
    __shared__ float s_h1[256];
    __shared__ float red[16];
    int bg = blockIdx.x, q = blockIdx.y, t = threadIdx.x;
    int tt = t & 255, grp = t >> 8;

    float og = 0.0f;
    #pragma unroll
    for (int s = 0; s < 8; ++s)
        og += OGP[((size_t)bg * 32 + grp * 8 + s) * 256 + tt];
    s_part[grp][tt] = og;
    __syncthreads();
    if (grp == 0) s_og[tt] = s_part[0][tt] + s_part[1][tt] + s_part[2][tt] + s_part[3][tt];
    __syncthreads();

    float x = 0.0f;
    {
        int k0 = grp * 64;
        #pragma unroll 16
        for (int k = k0; k < k0 + 64; ++k) x += s_og[k] * ga_wo[(size_t)k * 256 + tt];
    }
    s_part[grp][tt] = x;
    __syncthreads();
    int b = bg >> 5;
    size_t row = (size_t)b * ROWS_B + LS + (bg & 31);
    float res = latents[row * 256 + tt]
              + s_part[0][tt] + s_part[1][tt] + s_part[2][tt] + s_part[3][tt] + ga_bo[tt];

    float a = res, b2s = res * res;
    #pragma unroll
    for (int m = 32; m >= 1; m >>= 1) { a += __shfl_xor(a, m); b2s += __shfl_xor(b2s, m); }
    if ((t & 63) == 0 && t < 256) { red[t >> 6] = a; red[8 + (t >> 6)] = b2s; }
    __syncthreads();
    float mean = (red[0] + red[1] + red[2] + red[3]) * (1.0f / 256.0f);
    float var  = (red[8] + red[9] + red[10] + red[11]) * (1.0f / 256.0f) - mean * mean;
    float y = (res - mean) * rsqrtf(var + 1e-5f) * ln4g[tt] + ln4b[tt];
    if (grp == 0) s_y[tt] = y;
    __syncthreads();

    float h1p = 0.0f;
    {
        int k0 = grp * 64;
        #pragma unroll 16
        for (int k = k0; k < k0 + 64; ++k) h1p += s_y[k] * w1[(size_t)k * 1024 + q * 256 + tt];
    }
    s_part[grp][tt] = h1p;
    __syncthreads();
    if (grp == 0)
        s_h1[tt] = gelu_f(b1[q * 256 + tt]
                 + s_part[0][tt] + s_part[1][tt] + s_part[2][tt] + s_part[3][tt]);
    __syncthreads();

    float o = 0.0f;
    {
        int j0 = grp * 64;
        #pragma unroll 16
        for (int j = j0; j < j0 + 64; ++j) o += s_h1[j] * w2[(size_t)(q * 256 + j) * 256 + tt];
    }
    s_part[grp][tt] = o;
    __syncthreads();
    if (grp == 0) {
        float v = s_part[0][tt] + s_part[1][tt] + s_part[2][tt] + s_part[3][tt];
        if (q == 0) v += res + b2[tt];
        GTP[((size_t)bg * 4 + q) * 256 + tt] = v;
    }
}

__global__ __launch_bounds__(256) void glob_fin_k(
    const float* __restrict__ GTP, float* __restrict__ out)
{
    int bg = blockIdx.x, t = threadIdx.x;
    int b = bg >> 5;
    size_t row = (size_t)b * ROWS_B + LS + (bg & 31);
    float v = GTP[((size_t)bg * 4 + 0) * 256 + t] + GTP[((size_t)bg * 4 + 1) * 256 + t]
            + GTP[((size_t)bg * 4 + 2) * 256 + t] + GTP[((size_t)bg * 4 + 3) * 256 + t];
    out[row * 256 + t] = v;
}

// ---------------- launch ----------------
extern "C" void kernel_launch(void* const* d_in, const int* in_sizes, int n_in,
                              void* d_out, int out_size, void* d_ws, size_t ws_size,
                              hipStream_t stream)
{
    const float* latents = (const float*)d_in[0];
    const int*   idx     = (const int*)d_in[1];
    const float* rpe     = (const float*)d_in[2];
    const float* srpe    = (const float*)d_in[3];
    const float* dist    = (const float*)d_in[4];
    const float* sa_wq   = (const float*)d_in[6];
    const float* sa_wk   = (const float*)d_in[7];
    const float* sa_wv   = (const float*)d_in[8];
    const float* sa_wo   = (const float*)d_in[9];
    const float* sa_bo   = (const float*)d_in[10];
    const float* lsig    = (const float*)d_in[11];
    const float* gbias   = (const float*)d_in[12];
    const float* ln1g    = (const float*)d_in[13];
    const float* ln1b    = (const float*)d_in[14];
    const float* ln2g    = (const float*)d_in[15];
    const float* ln2b    = (const float*)d_in[16];
    const float* sff_w1  = (const float*)d_in[17];
    const float* sff_b1  = (const float*)d_in[18];
    const float* sff_w2  = (const float*)d_in[19];
    const float* sff_b2  = (const float*)d_in[20];
    const float* ga_wq   = (const float*)d_in[21];
    const float* ga_wk   = (const float*)d_in[22];
    const float* ga_wv   = (const float*)d_in[23];
    const float* ga_wo   = (const float*)d_in[24];
    const float* ga_bo   = (const float*)d_in[25];
    const float* ln3g    = (const float*)d_in[27];
    const float* ln3b    = (const float*)d_in[28];
    const float* ln4g    = (const float*)d_in[29];
    const float* ln4b    = (const float*)d_in[30];
    const float* gff_w1  = (const float*)d_in[31];
    const float* gff_b1  = (const float*)d_in[32];
    const float* gff_w2  = (const float*)d_in[33];
    const float* gff_b2  = (const float*)d_in[34];
    float* out = (float*)d_out;

    const size_t SZ = (size_t)4096 * 256;
    float* ws = (float*)d_ws;
    float* X = ws;                                         // [0, SZ)
    unsigned short* QKV2b = (unsigned short*)(ws + SZ);    // [SZ,4SZ) bf16 [4096][1536]
    unsigned short* H1b  = QKV2b;                          // overlays after attn
    unsigned short* KVGb = QKV2b;                          // overlays after ff2
    unsigned short* ORb  = (unsigned short*)(ws + 4 * SZ); // [4SZ,4.5SZ) bf16 [4096][512]
    float* A2  = ws + 5 * SZ;                              // [5SZ, ~6.02SZ)
    float* OGP = A2 + (size_t)2 * NH * NG * ROWS_B;        // [64*32][256]
    float* GTP = OGP + (size_t)64 * 32 * 256;              // [64*4][256]
    unsigned short* wt = (unsigned short*)(ws + 7 * SZ);
    unsigned short* wt_qkvw = wt;                          // [1024][256]
    unsigned short* wgs_w   = wt + 262144;                 // [512][256] (contiguous -> N=1536)
    unsigned short* wt_ff1  = wt + 393216;                 // [1024][256]
    unsigned short* wt_ff2  = wt + 655360;                 // [256][1024]
    unsigned short* wt_gakv = wt + 917504;                 // [768][256]
    unsigned short* wt_wo2  = wt + 1114112;                // [256][512]
    float* smalls = ws + 8 * SZ;
    unsigned short* KVGLb = (unsigned short*)smalls;       // bf16 [64][512]
    float* GQ = smalls + 16384;                            // f32 [64][256]
    unsigned short* GKVQb = (unsigned short*)(GQ + 16384); // bf16 [64][768]

    dim3 blk(256);

    WTab tab;
    tab.e[0] = { sa_wq,  wt_qkvw,           256,  256,   0 };
    tab.e[1] = { sa_wk,  wt_qkvw + 65536,   256,  256,  16 };
    tab.e[2] = { sa_wv,  wt_qkvw + 131072,  256,  256,  32 };
    tab.e[3] = { sff_w1, wt_ff1,            256, 1024,  48 };
    tab.e[4] = { sff_w2, wt_ff2,           1024,  256, 112 };
    tab.e[5] = { ga_wk,  wt_gakv,           256,  256, 176 };
    tab.e[6] = { ga_wv,  wt_gakv + 65536,   256,  256, 192 };
    tab.e[7] = { ga_wq,  wt_gakv + 131072,  256,  256, 208 };
    tab.e[8] = { sa_wq,  wt_qkvw,           256,  256, 1 << 30 };

    // merged prep: wspecial + wconv + ln1/ln3
    wprep_k<<<dim3(4896), blk, 0, stream>>>(tab, sa_wq, sa_wk, sa_wv, sa_wo,
                                            wt_qkvw, wt_wo2, latents,
                                            ln1g, ln1b, ln3g, ln3b, X, GQ);

    // spatial-attn glob K|V (bf16), then glob-score fold weights
    mgemm_k<0,0,0,0,1><<<dim3(8,1), blk, 0, stream>>>(latents, wt_qkvw + 65536, nullptr, nullptr, KVGLb,
        64,512,256,256, 32,ROWS_B,LS, 64,64,0);
    wgs_k<<<dim3(512), blk, 0, stream>>>(wt_qkvw, KVGLb, wgs_w);

    // QKV + qw + glob-scores in ONE GEMM (N=1536, bf16 out, 128-row tile)
    mgemm128_k<0,0,0,0,1><<<dim3(24,32), blk, 0, stream>>>(X, wt_qkvw, nullptr, nullptr, QKV2b,
        4096,QSTR,256,256, 4096,4096,0, 4096,4096,0);

    // fused spatial attention -> ORb = [O_base | R] (bf16)
    attn_sp_k<<<dim3(4096), blk, 0, stream>>>(QKV2b, KVGLb, idx, rpe, srpe, dist,
                                              lsig, gbias, ORb);

    // spatial residual: out = latents + ORb @ [Wo;Wvo] + bo
    mgemm128_k<1,0,1,1,0><<<dim3(4,32), blk, 0, stream>>>(ORb, wt_wo2, sa_bo, latents, out,
        4096,256,512,512, 4096,4096,0, LS,ROWS_B,0);

    // spatial FF
    ln_rows_k<<<dim3(4096), blk, 0, stream>>>(out, ln2g, ln2b, X);
    mgemm128_k<1,1,0,0,1><<<dim3(16,32), blk, 0, stream>>>(X, wt_ff1, sff_b1, nullptr, H1b,
        4096,1024,256,256, 4096,4096,0, 4096,4096,0);
    mgemm128_k<1,0,1,1,0><<<dim3(4,32), blk, 0, stream>>>(H1b, wt_ff2, sff_b2, out, out,
        4096,256,1024,1024, 4096,4096,0, LS,ROWS_B,0);

    // global attention projections (bf16 outputs)
    mgemm128_k<0,0,0,0,1><<<dim3(8,32), blk, 0, stream>>>(out, wt_gakv, nullptr, nullptr, KVGb,
        4096,512,256,256, LS,ROWS_B,0, 4096,4096,0);
    mgemm_k<0,0,0,0,1><<<dim3(12,1), blk, 0, stream>>>(GQ, wt_gakv, nullptr, nullptr, GKVQb,
        64,768,256,256, 64,64,0, 64,64,0);

    // global attention
    ga_scores_k<<<dim3(16, 33), blk, 0, stream>>>(GKVQb, KVGb, A2);
    ga_softmax_k<<<dim3(512), blk, 0, stream>>>(A2);
    ga_wv_k<<<dim3(64, 32), blk, 0, stream>>>(A2, GKVQb, KVGb, OGP);

    // glob tail: 4-way sliced + final combine
    glob_tail_k<<<dim3(64, 4), dim3(1024), 0, stream>>>(OGP, latents, ga_wo, ga_bo, ln4g, ln4b,
                                                        gff_w1, gff_b1, gff_w2, gff_b2, GTP);
    glob_fin_k<<<dim3(64), blk, 0, stream>>>(GTP, out);
}

// Round 13
// 161.207 us; speedup vs baseline: 1.1312x; 1.1312x over previous
//
#include <hip/hip_runtime.h>
#include <math.h>

// B=2, LS=2048, G=32, KNN=16, DIM=256, PE=32, H=8, DH=32, INNER=256, FF=1024
#define LS 2048
#define NG 32
#define ROWS_B 2080
#define DIM 256
#define PE 32
#define NH 8
#define DH 32
#define NCTX 49
#define SCALE 0.17677669529663687f  // 1/sqrt(32)
#define QSTR 1536                   // QKV2 row stride: q|k|v|qw|gs

typedef __attribute__((ext_vector_type(8))) short short8;
typedef __attribute__((ext_vector_type(4))) float f32x4;
typedef __attribute__((ext_vector_type(4))) unsigned short us4;

__device__ __forceinline__ unsigned short f2bf(float x)
{
    unsigned int u = __float_as_uint(x);
    unsigned int r = (u + 0x7fffu + ((u >> 16) & 1u)) >> 16;
    return (unsigned short)r;
}
__device__ __forceinline__ float bf2f(unsigned short v)
{
    return __uint_as_float((unsigned int)v << 16);
}
__device__ __forceinline__ float4 bf2f4(us4 v)
{
    return (float4){ bf2f(v.x), bf2f(v.y), bf2f(v.z), bf2f(v.w) };
}
__device__ __forceinline__ float dot4(float4 a, float4 b)
{
    return a.x * b.x + a.y * b.y + a.z * b.z + a.w * b.w;
}
__device__ __forceinline__ float gelu_f(float x)
{
    float x3 = x * x * x;
    return 0.5f * x * (1.0f + tanhf(0.7978845608028654f * (x + 0.044715f * x3)));
}

struct WEnt { const float* src; unsigned short* dst; int K; int N; int t0; };
struct WTab { WEnt e[9]; };

// ---------------- merged prep: wspecial (512) + wconv (224) + ln1/ln3 (4160) ----------------
__global__ __launch_bounds__(256) void wprep_k(
    WTab tab,
    const float* __restrict__ sa_wq, const float* __restrict__ sa_wk,
    const float* __restrict__ sa_wv, const float* __restrict__ sa_wo,
    unsigned short* __restrict__ wt_qkvw, unsigned short* __restrict__ wt_wo2,
    const float* __restrict__ latents,
    const float* __restrict__ g1, const float* __restrict__ b1,
    const float* __restrict__ g3, const float* __restrict__ b3,
    float* __restrict__ X, float* __restrict__ GQ)
{
    __shared__ unsigned short tile[64][72];
    __shared__ float red[8];
    int blk = blockIdx.x, t = threadIdx.x;
    if (blk < 512) {
        const float* wkpe = sa_wk + 256 * 256;
        const float* wvpe = sa_wv + 256 * 256;
        if (blk < 256) {
            int j = blk, h = j >> 5, p = j & 31;
            const float* wq = sa_wq + (size_t)t * 256 + h * 32;
            const float* wk = wkpe + (size_t)p * 256 + h * 32;
            float acc = 0.0f;
            #pragma unroll
            for (int dd = 0; dd < 32; ++dd) acc += wq[dd] * wk[dd];
            wt_qkvw[(size_t)(768 + j) * 256 + t] = f2bf(acc);
        } else {
            int n = blk - 256;
            #pragma unroll
            for (int kk = 0; kk < 2; ++kk) {
                int k = t + kk * 256;
                float v;
                if (k < 256) v = sa_wo[(size_t)k * 256 + n];
                else {
                    int j = k - 256, h = j >> 5, p = j & 31;
                    float a = 0.0f;
                    #pragma unroll
                    for (int dd = 0; dd < 32; ++dd)
                        a += wvpe[(size_t)p * 256 + h * 32 + dd] * sa_wo[(size_t)(h * 32 + dd) * 256 + n];
                    v = a;
                }
                wt_wo2[(size_t)n * 512 + k] = f2bf(v);
            }
        }
    } else if (blk < 736) {
        int local0 = blk - 512;
        int i = 0;
        #pragma unroll
        for (int j = 1; j < 9; ++j) if (local0 >= tab.e[j].t0) i = j;
        const float* W = tab.e[i].src;
        unsigned short* Wt = tab.e[i].dst;
        int K = tab.e[i].K, N = tab.e[i].N;
        int local = local0 - tab.e[i].t0;
        int nb = N >> 6;
        int n0 = (local % nb) * 64, k0 = (local / nb) * 64;
        #pragma unroll
        for (int r = 0; r < 4; ++r) {
            int k = r * 16 + (t >> 4);
            int n = (t & 15) * 4;
            float4 wv = *(const float4*)(W + (size_t)(k0 + k) * N + n0 + n);
            tile[k][n + 0] = f2bf(wv.x);
            tile[k][n + 1] = f2bf(wv.y);
            tile[k][n + 2] = f2bf(wv.z);
            tile[k][n + 3] = f2bf(wv.w);
        }
        __syncthreads();
        #pragma unroll
        for (int r = 0; r < 4; ++r) {
            int n = r * 16 + (t >> 4);
            int k = (t & 15) * 4;
            us4 o;
            o.x = tile[k + 0][n];
            o.y = tile[k + 1][n];
            o.z = tile[k + 2][n];
            o.w = tile[k + 3][n];
            *(us4*)(Wt + (size_t)(n0 + n) * K + k0 + k) = o;
        }
    } else {
        int blk2 = blk - 736;
        const float* gam; const float* bet; size_t ip; float* op;
        if (blk2 < 4096) {
            int b = blk2 >> 11;
            ip = ((size_t)b * ROWS_B + (blk2 & 2047)) * DIM + t;
            op = X + (size_t)blk2 * DIM + t;
            gam = g1; bet = b1;
        } else {
            int r2 = blk2 - 4096;
            int b = r2 >> 5;
            ip = ((size_t)b * ROWS_B + LS + (r2 & 31)) * DIM + t;
            op = GQ + (size_t)r2 * DIM + t;
            gam = g3; bet = b3;
        }
        float v = latents[ip];
        float a = v, b2 = v * v;
        #pragma unroll
        for (int m = 32; m >= 1; m >>= 1) { a += __shfl_xor(a, m); b2 += __shfl_xor(b2, m); }
        if ((t & 63) == 0) { red[t >> 6] = a; red[4 + (t >> 6)] = b2; }
        __syncthreads();
        float mean = (red[0] + red[1] + red[2] + red[3]) * (1.0f / 256.0f);
        float var  = (red[4] + red[5] + red[6] + red[7]) * (1.0f / 256.0f) - mean * mean;
        *op = (v - mean) * rsqrtf(var + 1e-5f) * gam[t] + bet[t];
    }
}

// ---------------- plain LN (ln2) ----------------
__global__ __launch_bounds__(256) void ln_rows_k(
    const float* __restrict__ in, const float* __restrict__ gam,
    const float* __restrict__ bet, float* __restrict__ out)
{
    __shared__ float red[8];
    int r = blockIdx.x, t = threadIdx.x;
    int b = r >> 11;
    size_t ip = ((size_t)b * ROWS_B + (r & 2047)) * DIM + t;
    float v = in[ip];
    float a = v, b2 = v * v;
    #pragma unroll
    for (int m = 32; m >= 1; m >>= 1) { a += __shfl_xor(a, m); b2 += __shfl_xor(b2, m); }
    if ((t & 63) == 0) { red[t >> 6] = a; red[4 + (t >> 6)] = b2; }
    __syncthreads();
    float mean = (red[0] + red[1] + red[2] + red[3]) * (1.0f / 256.0f);
    float var  = (red[4] + red[5] + red[6] + red[7]) * (1.0f / 256.0f) - mean * mean;
    out[(size_t)r * DIM + t] = (v - mean) * rsqrtf(var + 1e-5f) * gam[t] + bet[t];
}

// ---------------- wgs: glob-score fold weights (stored contiguously after wt_qkvw) ----
__global__ __launch_bounds__(256) void wgs_k(
    const unsigned short* __restrict__ wtq, const unsigned short* __restrict__ kvglb,
    unsigned short* __restrict__ wgs)
{
    int n = blockIdx.x, k = threadIdx.x;
    int h = n & 7, cg = n >> 3;
    float acc = 0.0f;
    #pragma unroll
    for (int dd = 0; dd < 32; ++dd)
        acc += bf2f(wtq[(size_t)(h * 32 + dd) * 256 + k]) * bf2f(kvglb[(size_t)cg * 512 + h * 32 + dd]);
    wgs[(size_t)n * 256 + k] = f2bf(acc);
}

// ---------------- bf16 MFMA GEMM, 64x64 tile ----------------
template<int BIAS, int DOGELU, int RES, int ABF16, int CBF16>
__global__ __launch_bounds__(256) void mgemm_k(
    const void* __restrict__ Av, const unsigned short* __restrict__ Bt,
    const float* __restrict__ bias, const float* __restrict__ Res,
    void* __restrict__ Cv, int M, int N, int K, int bstr,
    int arpb, int absr, int aoff, int crpb, int cbsr, int coff)
{
    __shared__ unsigned short Asl[64][64];
    __shared__ unsigned short Bsl[64][64];
    int t = threadIdx.x;
    int col0 = blockIdx.x * 64, row0 = blockIdx.y * 64;
    int lane = t & 63, w = t >> 6;
    int wr = w >> 1, wc = w & 1;
    int lrow = lane & 15, lk = lane >> 4;

    int srow = t >> 4;
    int scol = (t & 15) << 2;
    int sslot = (t & 15) >> 1;
    int shalf = (t & 15) & 1;

    f32x4 acc[2][2];
    #pragma unroll
    for (int m = 0; m < 2; ++m)
        #pragma unroll
        for (int n = 0; n < 2; ++n)
            acc[m][n] = (f32x4){0.f, 0.f, 0.f, 0.f};

    for (int kk = 0; kk < K; kk += 64) {
        #pragma unroll
        for (int r = 0; r < 4; ++r) {
            int row = r * 16 + srow;
            int ar = row0 + row;
            size_t ab = ((size_t)(ar / arpb) * absr + aoff + (ar % arpb)) * (size_t)K + kk + scol;
            us4 ap;
            if (ABF16) {
                ap = *(const us4*)((const unsigned short*)Av + ab);
            } else {
                float4 av = *(const float4*)((const float*)Av + ab);
                ap.x = f2bf(av.x); ap.y = f2bf(av.y); ap.z = f2bf(av.z); ap.w = f2bf(av.w);
            }
            *(us4*)&Asl[row][((sslot ^ (row & 7)) << 3) + (shalf << 2)] = ap;
            us4 bv = *(const us4*)(Bt + (size_t)(col0 + row) * bstr + kk + scol);
            *(us4*)&Bsl[row][((sslot ^ (row & 7)) << 3) + (shalf << 2)] = bv;
        }
        __syncthreads();
        #pragma unroll
        for (int k2 = 0; k2 < 2; ++k2) {
            short8 af[2], bfr[2];
            #pragma unroll
            for (int m = 0; m < 2; ++m) {
                int rowA = wr * 32 + m * 16 + lrow;
                af[m] = *(short8*)&Asl[rowA][((k2 * 4 + lk) ^ (rowA & 7)) << 3];
                int rowB = wc * 32 + m * 16 + lrow;
                bfr[m] = *(short8*)&Bsl[rowB][((k2 * 4 + lk) ^ (rowB & 7)) << 3];
            }
            #pragma unroll
            for (int m = 0; m < 2; ++m)
                #pragma unroll
                for (int n = 0; n < 2; ++n)
                    acc[m][n] = __builtin_amdgcn_mfma_f32_16x16x32_bf16(af[m], bfr[n], acc[m][n], 0, 0, 0);
        }
        __syncthreads();
    }
    #pragma unroll
    for (int m = 0; m < 2; ++m) {
        #pragma unroll
        for (int n = 0; n < 2; ++n) {
            int col = col0 + wc * 32 + n * 16 + lrow;
            #pragma unroll
            for (int j = 0; j < 4; ++j) {
                int r = row0 + wr * 32 + m * 16 + lk * 4 + j;
                size_t cp = ((size_t)(r / crpb) * cbsr + coff + (r % crpb)) * (size_t)N + col;
                float o = acc[m][n][j];
                if (BIAS)   o += bias[col];
                if (DOGELU) o = gelu_f(o);
                if (RES)    o += Res[cp];
                if (CBF16) ((unsigned short*)Cv)[cp] = f2bf(o);
                else       ((float*)Cv)[cp] = o;
            }
        }
    }
}

// ---------------- fused spatial attention (QKV2 stride 1536, GS inline at +1024) ----------------
__global__ __launch_bounds__(256) void attn_sp_k(
    const unsigned short* __restrict__ QKV, const unsigned short* __restrict__ KVGLb,
    const int* __restrict__ idx, const float* __restrict__ rpe,
    const float* __restrict__ srpe, const float* __restrict__ dist,
    const float* __restrict__ lsig, const float* __restrict__ gbias,
    unsigned short* __restrict__ ORb)
{
    __shared__ float s_rpe[17 * 32];
    __shared__ float s_sc[NCTX * 8];
    __shared__ float s_red[32 * 64];
    __shared__ float s_d[16];
    __shared__ int   s_row[17];
    int t = threadIdx.x;
    int r = blockIdx.x;
    int b = r >> 11;
    int w = t >> 6, lane = t & 63;
    int h = lane >> 3, dg = lane & 7;

    if (t < 32) s_rpe[t] = srpe[(size_t)r * 32 + t];
    for (int i = t; i < 512; i += 256) s_rpe[32 + i] = rpe[(size_t)r * 512 + i];
    if (t < 16) {
        s_row[t + 1] = (b << 11) + idx[r * 16 + t];
        s_d[t] = dist[(size_t)r * 16 + t];
    }
    if (t == 16) s_row[0] = r;

    size_t qb = (size_t)r * QSTR + lane * 4;
    float4 q4  = bf2f4(*(const us4*)(QKV + qb));
    float4 qw4 = bf2f4(*(const us4*)(QKV + qb + 768));
    float inv2s = 1.0f / (2.0f * __expf(2.0f * lsig[h]));
    float gb = gbias[0];
    __syncthreads();

    us4 kreg[5];
    #pragma unroll
    for (int i = 0; i < 5; ++i) {
        int c = w + 4 * i;
        if (c < 17) kreg[i] = *(const us4*)(QKV + (size_t)s_row[c] * QSTR + 256 + lane * 4);
    }
    float sc_loc[5];
    #pragma unroll
    for (int i = 0; i < 5; ++i) {
        int c = w + 4 * i;
        if (c < 17) {
            float4 k4 = bf2f4(kreg[i]);
            float4 rv4 = *(const float4*)&s_rpe[c * 32 + dg * 4];
            float part = dot4(q4, k4) + dot4(rv4, qw4);
            part += __shfl_xor(part, 1);
            part += __shfl_xor(part, 2);
            part += __shfl_xor(part, 4);
            float bia = (c == 0) ? 0.0f : -s_d[c - 1] * s_d[c - 1] * inv2s;
            float sval = part * SCALE + bia;
            if (dg == 0) s_sc[c * 8 + h] = sval;
            sc_loc[i] = sval;
        }
    }
    float sc_glob[8];
    #pragma unroll
    for (int i = 0; i < 8; ++i) {
        int gi = w + 4 * i;
        float sval = bf2f(QKV[(size_t)r * QSTR + 1024 + (((size_t)b * 32 + gi) << 3) + h]) * SCALE + gb;
        if (dg == 0) s_sc[(17 + gi) * 8 + h] = sval;
        sc_glob[i] = sval;
    }
    __syncthreads();

    float vals[7];
    float lm = -3.0e38f;
    #pragma unroll
    for (int i = 0; i < 7; ++i) {
        int cc = dg + 8 * i;
        if (cc < NCTX) { float v = s_sc[cc * 8 + h]; vals[i] = v; lm = fmaxf(lm, v); }
    }
    lm = fmaxf(lm, __shfl_xor(lm, 1));
    lm = fmaxf(lm, __shfl_xor(lm, 2));
    lm = fmaxf(lm, __shfl_xor(lm, 4));
    float ls = 0.0f;
    #pragma unroll
    for (int i = 0; i < 7; ++i) {
        int cc = dg + 8 * i;
        if (cc < NCTX) ls += __expf(vals[i] - lm);
    }
    ls += __shfl_xor(ls, 1);
    ls += __shfl_xor(ls, 2);
    ls += __shfl_xor(ls, 4);
    float inv = 1.0f / ls;

    us4 vreg[5];
    #pragma unroll
    for (int i = 0; i < 5; ++i) {
        int c = w + 4 * i;
        if (c < 17) vreg[i] = *(const us4*)(QKV + (size_t)s_row[c] * QSTR + 512 + lane * 4);
    }
    float4 acc4 = (float4){0, 0, 0, 0}, racc4 = (float4){0, 0, 0, 0};
    #pragma unroll
    for (int i = 0; i < 5; ++i) {
        int c = w + 4 * i;
        if (c < 17) {
            float p = __expf(sc_loc[i] - lm);
            float4 v4 = bf2f4(vreg[i]);
            float4 rv4 = *(const float4*)&s_rpe[c * 32 + dg * 4];
            racc4.x += p * rv4.x; racc4.y += p * rv4.y;
            racc4.z += p * rv4.z; racc4.w += p * rv4.w;
            acc4.x += p * v4.x; acc4.y += p * v4.y;
            acc4.z += p * v4.z; acc4.w += p * v4.w;
        }
    }
    #pragma unroll
    for (int i = 0; i < 8; ++i) {
        int gi = w + 4 * i;
        float p = __expf(sc_glob[i] - lm);
        float4 v4 = bf2f4(*(const us4*)(KVGLb + ((size_t)(b * NG + gi)) * 512 + 256 + lane * 4));
        acc4.x += p * v4.x; acc4.y += p * v4.y;
        acc4.z += p * v4.z; acc4.w += p * v4.w;
    }

    s_red[(w * 8 + 0) * 64 + lane] = acc4.x;
    s_red[(w * 8 + 1) * 64 + lane] = acc4.y;
    s_red[(w * 8 + 2) * 64 + lane] = acc4.z;
    s_red[(w * 8 + 3) * 64 + lane] = acc4.w;
    s_red[(w * 8 + 4) * 64 + lane] = racc4.x;
    s_red[(w * 8 + 5) * 64 + lane] = racc4.y;
    s_red[(w * 8 + 6) * 64 + lane] = racc4.z;
    s_red[(w * 8 + 7) * 64 + lane] = racc4.w;
    __syncthreads();
    {
        int j = w;
        float a = 0.0f, rr = 0.0f;
        #pragma unroll
        for (int ww = 0; ww < 4; ++ww) {
            a  += s_red[(ww * 8 + j) * 64 + lane];
            rr += s_red[(ww * 8 + 4 + j) * 64 + lane];
        }
        int e = h * 32 + dg * 4 + j;
        ORb[(size_t)r * 512 + e]       = f2bf(a * inv);
        ORb[(size_t)r * 512 + 256 + e] = f2bf(rr * inv);
    }
}

// ---------------- global attention: scores via MFMA ----------------
__global__ __launch_bounds__(256) void ga_scores_k(
    const unsigned short* __restrict__ GKVQ, const unsigned short* __restrict__ KVG,
    float* __restrict__ A2)
{
    int t = threadIdx.x;
    int bh = blockIdx.x;
    int b = bh >> 3, h = bh & 7;
    int w = t >> 6, lane = t & 63;
    int ct = blockIdx.y * 4 + w;
    if (ct >= 130) return;
    int lr = lane & 15, lq = lane >> 4;

    short8 aq0 = *(const short8*)(GKVQ + ((size_t)(b * 32 + lr)) * 768 + 512 + h * 32 + lq * 8);
    short8 aq1 = *(const short8*)(GKVQ + ((size_t)(b * 32 + 16 + lr)) * 768 + 512 + h * 32 + lq * 8);
    int c = ct * 16 + lr;
    const unsigned short* kr = (c < LS)
        ? KVG + ((size_t)(b * LS + c)) * 512 + h * 32 + lq * 8
        : GKVQ + ((size_t)(b * NG + (c - LS))) * 768 + h * 32 + lq * 8;
    short8 bk = *(const short8*)kr;

    f32x4 acc0 = (f32x4){0, 0, 0, 0}, acc1 = (f32x4){0, 0, 0, 0};
    acc0 = __builtin_amdgcn_mfma_f32_16x16x32_bf16(aq0, bk, acc0, 0, 0, 0);
    acc1 = __builtin_amdgcn_mfma_f32_16x16x32_bf16(aq1, bk, acc1, 0, 0, 0);

    float* arow = A2 + ((size_t)(b * NH + h) * NG) * ROWS_B + ct * 16 + lr;
    #pragma unroll
    for (int j = 0; j < 4; ++j) {
        arow[(size_t)(lq * 4 + j) * ROWS_B]        = acc0[j] * SCALE;
        arow[(size_t)(16 + lq * 4 + j) * ROWS_B]   = acc1[j] * SCALE;
    }
}

// ---------------- global attention: row softmax over 2080 ----------------
__global__ __launch_bounds__(256) void ga_softmax_k(float* __restrict__ A2)
{
    __shared__ float red[8];
    int t = threadIdx.x;
    float* row = A2 + (size_t)blockIdx.x * ROWS_B;
    float lm = -1e30f;
    for (int i = t; i < ROWS_B; i += 256) lm = fmaxf(lm, row[i]);
    #pragma unroll
    for (int m = 32; m >= 1; m >>= 1) lm = fmaxf(lm, __shfl_xor(lm, m));
    if ((t & 63) == 0) red[t >> 6] = lm;
    __syncthreads();
    float M = fmaxf(fmaxf(red[0], red[1]), fmaxf(red[2], red[3]));
    float ls = 0.0f;
    for (int i = t; i < ROWS_B; i += 256) {
        float e = __expf(row[i] - M);
        row[i] = e;
        ls += e;
    }
    #pragma unroll
    for (int m = 32; m >= 1; m >>= 1) ls += __shfl_xor(ls, m);
    if ((t & 63) == 0) red[4 + (t >> 6)] = ls;
    __syncthreads();
    float inv = 1.0f / (red[4] + red[5] + red[6] + red[7]);
    for (int i = t; i < ROWS_B; i += 256) row[i] *= inv;
}

// ---------------- global attention: weighted V (32-way split-K, bf16) ----------------
__global__ __launch_bounds__(256) void ga_wv_k(
    const float* __restrict__ A2, const unsigned short* __restrict__ GKVQ,
    const unsigned short* __restrict__ KVG, float* __restrict__ OGP)
{
    __shared__ float s_acc[8][256];
    int t = threadIdx.x;
    int bg = blockIdx.x;       // b*32+g
    int s = blockIdx.y;        // 0..31
    int b = bg >> 5, g = bg & 31;
    int tt = t & 31, sub = t >> 5;
    int h = tt >> 2;
    const float* w = A2 + ((size_t)(b * NH + h) * NG + g) * ROWS_B;
    int c0 = s * 65, cend = c0 + 65;
    float acc[8] = {};
    for (int c = c0 + sub; c < cend; c += 8) {
        float p = w[c];
        const unsigned short* vr = (c < LS)
            ? KVG + ((size_t)(b * LS + c)) * 512 + 256 + tt * 8
            : GKVQ + ((size_t)(b * NG + (c - LS))) * 768 + 256 + tt * 8;
        us4 v0 = *(const us4*)vr;
        us4 v1 = *(const us4*)(vr + 4);
        acc[0] += p * bf2f(v0.x); acc[1] += p * bf2f(v0.y);
        acc[2] += p * bf2f(v0.z); acc[3] += p * bf2f(v0.w);
        acc[4] += p * bf2f(v1.x); acc[5] += p * bf2f(v1.y);
        acc[6] += p * bf2f(v1.z); acc[7] += p * bf2f(v1.w);
    }
    #pragma unroll
    for (int j = 0; j < 8; ++j) s_acc[sub][tt * 8 + j] = acc[j];
    __syncthreads();
    float o = 0.0f;
    #pragma unroll
    for (int ss = 0; ss < 8; ++ss) o += s_acc[ss][t];
    OGP[((size_t)bg * 32 + s) * 256 + t] = o;
}

// ---------------- glob tail, 4 blocks per row ----------------
__global__ __launch_bounds__(1024) void glob_tail_k(
    const float* __restrict__ OGP, const float* __restrict__ latents,
    const float* __restrict__ ga_wo, const float* __restrict__ ga_bo,
    const float* __restrict__ ln4g, const float* __restrict__ ln4b,
    const float* __restrict__ w1, const float* __restrict__ b1,
    const float* __restrict__ w2, const float* __restrict__ b2,
    float* __restrict__ GTP)
{
    __shared__ float s_part[4][256];
    __shared__ float s_og[256];
    __shared__ float s_y[256];
    __shared__ float s_h1[256];
    __shared__ float red[16];
    int bg = blockIdx.x, q = blockIdx.y, t = threadIdx.x;
    int tt = t & 255, grp = t >> 8;

    float og = 0.0f;
    #pragma unroll
    for (int s = 0; s < 8; ++s)
        og += OGP[((size_t)bg * 32 + grp * 8 + s) * 256 + tt];
    s_part[grp][tt] = og;
    __syncthreads();
    if (grp == 0) s_og[tt] = s_part[0][tt] + s_part[1][tt] + s_part[2][tt] + s_part[3][tt];
    __syncthreads();

    float x = 0.0f;
    {
        int k0 = grp * 64;
        #pragma unroll 16
        for (int k = k0; k < k0 + 64; ++k) x += s_og[k] * ga_wo[(size_t)k * 256 + tt];
    }
    s_part[grp][tt] = x;
    __syncthreads();
    int b = bg >> 5;
    size_t row = (size_t)b * ROWS_B + LS + (bg & 31);
    float res = latents[row * 256 + tt]
              + s_part[0][tt] + s_part[1][tt] + s_part[2][tt] + s_part[3][tt] + ga_bo[tt];

    float a = res, b2s = res * res;
    #pragma unroll
    for (int m = 32; m >= 1; m >>= 1) { a += __shfl_xor(a, m); b2s += __shfl_xor(b2s, m); }
    if ((t & 63) == 0 && t < 256) { red[t >> 6] = a; red[8 + (t >> 6)] = b2s; }
    __syncthreads();
    float mean = (red[0] + red[1] + red[2] + red[3]) * (1.0f / 256.0f);
    float var  = (red[8] + red[9] + red[10] + red[11]) * (1.0f / 256.0f) - mean * mean;
    float y = (res - mean) * rsqrtf(var + 1e-5f) * ln4g[tt] + ln4b[tt];
    if (grp == 0) s_y[tt] = y;
    __syncthreads();

    float h1p = 0.0f;
    {
        int k0 = grp * 64;
        #pragma unroll 16
        for (int k = k0; k < k0 + 64; ++k) h1p += s_y[k] * w1[(size_t)k * 1024 + q * 256 + tt];
    }
    s_part[grp][tt] = h1p;
    __syncthreads();
    if (grp == 0)
        s_h1[tt] = gelu_f(b1[q * 256 + tt]
                 + s_part[0][tt] + s_part[1][tt] + s_part[2][tt] + s_part[3][tt]);
    __syncthreads();

    float o = 0.0f;
    {
        int j0 = grp * 64;
        #pragma unroll 16
        for (int j = j0; j < j0 + 64; ++j) o += s_h1[j] * w2[(size_t)(q * 256 + j) * 256 + tt];
    }
    s_part[grp][tt] = o;
    __syncthreads();
    if (grp == 0) {
        float v = s_part[0][tt] + s_part[1][tt] + s_part[2][tt] + s_part[3][tt];
        if (q == 0) v += res + b2[tt];
        GTP[((size_t)bg * 4 + q) * 256 + tt] = v;
    }
}

__global__ __launch_bounds__(256) void glob_fin_k(
    const float* __restrict__ GTP, float* __restrict__ out)
{
    int bg = blockIdx.x, t = threadIdx.x;
    int b = bg >> 5;
    size_t row = (size_t)b * ROWS_B + LS + (bg & 31);
    float v = GTP[((size_t)bg * 4 + 0) * 256 + t] + GTP[((size_t)bg * 4 + 1) * 256 + t]
            + GTP[((size_t)bg * 4 + 2) * 256 + t] + GTP[((size_t)bg * 4 + 3) * 256 + t];
    out[row * 256 + t] = v;
}

// ---------------- launch ----------------
extern "C" void kernel_launch(void* const* d_in, const int* in_sizes, int n_in,
                              void* d_out, int out_size, void* d_ws, size_t ws_size,
                              hipStream_t stream)
{
    const float* latents = (const float*)d_in[0];
    const int*   idx     = (const int*)d_in[1];
    const float* rpe     = (const float*)d_in[2];
    const float* srpe    = (const float*)d_in[3];
    const float* dist    = (const float*)d_in[4];
    const float* sa_wq   = (const float*)d_in[6];
    const float* sa_wk   = (const float*)d_in[7];
    const float* sa_wv   = (const float*)d_in[8];
    const float* sa_wo   = (const float*)d_in[9];
    const float* sa_bo   = (const float*)d_in[10];
    const float* lsig    = (const float*)d_in[11];
    const float* gbias   = (const float*)d_in[12];
    const float* ln1g    = (const float*)d_in[13];
    const float* ln1b    = (const float*)d_in[14];
    const float* ln2g    = (const float*)d_in[15];
    const float* ln2b    = (const float*)d_in[16];
    const float* sff_w1  = (const float*)d_in[17];
    const float* sff_b1  = (const float*)d_in[18];
    const float* sff_w2  = (const float*)d_in[19];
    const float* sff_b2  = (const float*)d_in[20];
    const float* ga_wq   = (const float*)d_in[21];
    const float* ga_wk   = (const float*)d_in[22];
    const float* ga_wv   = (const float*)d_in[23];
    const float* ga_wo   = (const float*)d_in[24];
    const float* ga_bo   = (const float*)d_in[25];
    const float* ln3g    = (const float*)d_in[27];
    const float* ln3b    = (const float*)d_in[28];
    const float* ln4g    = (const float*)d_in[29];
    const float* ln4b    = (const float*)d_in[30];
    const float* gff_w1  = (const float*)d_in[31];
    const float* gff_b1  = (const float*)d_in[32];
    const float* gff_w2  = (const float*)d_in[33];
    const float* gff_b2  = (const float*)d_in[34];
    float* out = (float*)d_out;

    const size_t SZ = (size_t)4096 * 256;
    float* ws = (float*)d_ws;
    float* X = ws;                                         // [0, SZ)
    unsigned short* QKV2b = (unsigned short*)(ws + SZ);    // [SZ,4SZ) bf16 [4096][1536]
    unsigned short* H1b  = QKV2b;                          // overlays after attn
    unsigned short* KVGb = QKV2b;                          // overlays after ff2
    unsigned short* ORb  = (unsigned short*)(ws + 4 * SZ); // [4SZ,4.5SZ) bf16 [4096][512]
    float* A2  = ws + 5 * SZ;                              // [5SZ, ~6.02SZ)
    float* OGP = A2 + (size_t)2 * NH * NG * ROWS_B;        // [64*32][256]
    float* GTP = OGP + (size_t)64 * 32 * 256;              // [64*4][256]
    unsigned short* wt = (unsigned short*)(ws + 7 * SZ);
    unsigned short* wt_qkvw = wt;                          // [1024][256]
    unsigned short* wgs_w   = wt + 262144;                 // [512][256] (contiguous -> N=1536)
    unsigned short* wt_ff1  = wt + 393216;                 // [1024][256]
    unsigned short* wt_ff2  = wt + 655360;                 // [256][1024]
    unsigned short* wt_gakv = wt + 917504;                 // [768][256]
    unsigned short* wt_wo2  = wt + 1114112;                // [256][512]
    float* smalls = ws + 8 * SZ;
    unsigned short* KVGLb = (unsigned short*)smalls;       // bf16 [64][512]
    float* GQ = smalls + 16384;                            // f32 [64][256]
    unsigned short* GKVQb = (unsigned short*)(GQ + 16384); // bf16 [64][768]

    dim3 blk(256);

    WTab tab;
    tab.e[0] = { sa_wq,  wt_qkvw,           256,  256,   0 };
    tab.e[1] = { sa_wk,  wt_qkvw + 65536,   256,  256,  16 };
    tab.e[2] = { sa_wv,  wt_qkvw + 131072,  256,  256,  32 };
    tab.e[3] = { sff_w1, wt_ff1,            256, 1024,  48 };
    tab.e[4] = { sff_w2, wt_ff2,           1024,  256, 112 };
    tab.e[5] = { ga_wk,  wt_gakv,           256,  256, 176 };
    tab.e[6] = { ga_wv,  wt_gakv + 65536,   256,  256, 192 };
    tab.e[7] = { ga_wq,  wt_gakv + 131072,  256,  256, 208 };
    tab.e[8] = { sa_wq,  wt_qkvw,           256,  256, 1 << 30 };

    // merged prep: wspecial + wconv + ln1/ln3
    wprep_k<<<dim3(4896), blk, 0, stream>>>(tab, sa_wq, sa_wk, sa_wv, sa_wo,
                                            wt_qkvw, wt_wo2, latents,
                                            ln1g, ln1b, ln3g, ln3b, X, GQ);

    // spatial-attn glob K|V (bf16), then glob-score fold weights
    mgemm_k<0,0,0,0,1><<<dim3(8,1), blk, 0, stream>>>(latents, wt_qkvw + 65536, nullptr, nullptr, KVGLb,
        64,512,256,256, 32,ROWS_B,LS, 64,64,0);
    wgs_k<<<dim3(512), blk, 0, stream>>>(wt_qkvw, KVGLb, wgs_w);

    // QKV + qw + glob-scores in ONE GEMM (N=1536, bf16 out, 64-tile: 1536 blocks)
    mgemm_k<0,0,0,0,1><<<dim3(24,64), blk, 0, stream>>>(X, wt_qkvw, nullptr, nullptr, QKV2b,
        4096,QSTR,256,256, 4096,4096,0, 4096,4096,0);

    // fused spatial attention -> ORb = [O_base | R] (bf16)
    attn_sp_k<<<dim3(4096), blk, 0, stream>>>(QKV2b, KVGLb, idx, rpe, srpe, dist,
                                              lsig, gbias, ORb);

    // spatial residual: out = latents + ORb @ [Wo;Wvo] + bo
    mgemm_k<1,0,1,1,0><<<dim3(4,64), blk, 0, stream>>>(ORb, wt_wo2, sa_bo, latents, out,
        4096,256,512,512, 4096,4096,0, LS,ROWS_B,0);

    // spatial FF
    ln_rows_k<<<dim3(4096), blk, 0, stream>>>(out, ln2g, ln2b, X);
    mgemm_k<1,1,0,0,1><<<dim3(16,64), blk, 0, stream>>>(X, wt_ff1, sff_b1, nullptr, H1b,
        4096,1024,256,256, 4096,4096,0, 4096,4096,0);
    mgemm_k<1,0,1,1,0><<<dim3(4,64), blk, 0, stream>>>(H1b, wt_ff2, sff_b2, out, out,
        4096,256,1024,1024, 4096,4096,0, LS,ROWS_B,0);

    // global attention projections (bf16 outputs)
    mgemm_k<0,0,0,0,1><<<dim3(8,64), blk, 0, stream>>>(out, wt_gakv, nullptr, nullptr, KVGb,
        4096,512,256,256, LS,ROWS_B,0, 4096,4096,0);
    mgemm_k<0,0,0,0,1><<<dim3(12,1), blk, 0, stream>>>(GQ, wt_gakv, nullptr, nullptr, GKVQb,
        64,768,256,256, 64,64,0, 64,64,0);

    // global attention
    ga_scores_k<<<dim3(16, 33), blk, 0, stream>>>(GKVQb, KVGb, A2);
    ga_softmax_k<<<dim3(512), blk, 0, stream>>>(A2);
    ga_wv_k<<<dim3(64, 32), blk, 0, stream>>>(A2, GKVQb, KVGb, OGP);

    // glob tail: 4-way sliced + final combine
    glob_tail_k<<<dim3(64, 4), dim3(1024), 0, stream>>>(OGP, latents, ga_wo, ga_bo, ln4g, ln4b,
                                                        gff_w1, gff_b1, gff_w2, gff_b2, GTP);
    glob_fin_k<<<dim3(64), blk, 0, stream>>>(GTP, out);
}

// Round 14
// 139.810 us; speedup vs baseline: 1.3043x; 1.1530x over previous
//
#include <hip/hip_runtime.h>
#include <math.h>

// B=2, LS=2048, G=32, KNN=16, DIM=256, PE=32, H=8, DH=32, INNER=256, FF=1024
#define LS 2048
#define NG 32
#define ROWS_B 2080
#define DIM 256
#define PE 32
#define NH 8
#define DH 32
#define NCTX 49
#define SCALE 0.17677669529663687f  // 1/sqrt(32)
#define QSTR 1536                   // QKV2 row stride: q|k|v|qw|gs

typedef __attribute__((ext_vector_type(8))) short short8;
typedef __attribute__((ext_vector_type(4))) float f32x4;
typedef __attribute__((ext_vector_type(4))) unsigned short us4;

__device__ __forceinline__ unsigned short f2bf(float x)
{
    unsigned int u = __float_as_uint(x);
    unsigned int r = (u + 0x7fffu + ((u >> 16) & 1u)) >> 16;
    return (unsigned short)r;
}
__device__ __forceinline__ float bf2f(unsigned short v)
{
    return __uint_as_float((unsigned int)v << 16);
}
__device__ __forceinline__ float4 bf2f4(us4 v)
{
    return (float4){ bf2f(v.x), bf2f(v.y), bf2f(v.z), bf2f(v.w) };
}
__device__ __forceinline__ float dot4(float4 a, float4 b)
{
    return a.x * b.x + a.y * b.y + a.z * b.z + a.w * b.w;
}
__device__ __forceinline__ float gelu_f(float x)
{
    float x3 = x * x * x;
    return 0.5f * x * (1.0f + tanhf(0.7978845608028654f * (x + 0.044715f * x3)));
}

struct WEnt { const float* src; unsigned short* dst; int K; int N; int t0; };
struct WTab { WEnt e[9]; };

// ---------------- merged prep: wspecial (512) + wconv (224) + ln1/ln3 (4160) ----------------
// X written bf16 (bit-identical to GEMM-staging conversion); GQ stays f32.
__global__ __launch_bounds__(256) void wprep_k(
    WTab tab,
    const float* __restrict__ sa_wq, const float* __restrict__ sa_wk,
    const float* __restrict__ sa_wv, const float* __restrict__ sa_wo,
    unsigned short* __restrict__ wt_qkvw, unsigned short* __restrict__ wt_wo2,
    const float* __restrict__ latents,
    const float* __restrict__ g1, const float* __restrict__ b1,
    const float* __restrict__ g3, const float* __restrict__ b3,
    unsigned short* __restrict__ Xb, float* __restrict__ GQ)
{
    __shared__ unsigned short tile[64][72];
    __shared__ float red[8];
    int blk = blockIdx.x, t = threadIdx.x;
    if (blk < 512) {
        const float* wkpe = sa_wk + 256 * 256;
        const float* wvpe = sa_wv + 256 * 256;
        if (blk < 256) {
            int j = blk, h = j >> 5, p = j & 31;
            const float* wq = sa_wq + (size_t)t * 256 + h * 32;
            const float* wk = wkpe + (size_t)p * 256 + h * 32;
            float acc = 0.0f;
            #pragma unroll
            for (int dd = 0; dd < 32; ++dd) acc += wq[dd] * wk[dd];
            wt_qkvw[(size_t)(768 + j) * 256 + t] = f2bf(acc);
        } else {
            int n = blk - 256;
            #pragma unroll
            for (int kk = 0; kk < 2; ++kk) {
                int k = t + kk * 256;
                float v;
                if (k < 256) v = sa_wo[(size_t)k * 256 + n];
                else {
                    int j = k - 256, h = j >> 5, p = j & 31;
                    float a = 0.0f;
                    #pragma unroll
                    for (int dd = 0; dd < 32; ++dd)
                        a += wvpe[(size_t)p * 256 + h * 32 + dd] * sa_wo[(size_t)(h * 32 + dd) * 256 + n];
                    v = a;
                }
                wt_wo2[(size_t)n * 512 + k] = f2bf(v);
            }
        }
    } else if (blk < 736) {
        int local0 = blk - 512;
        int i = 0;
        #pragma unroll
        for (int j = 1; j < 9; ++j) if (local0 >= tab.e[j].t0) i = j;
        const float* W = tab.e[i].src;
        unsigned short* Wt = tab.e[i].dst;
        int K = tab.e[i].K, N = tab.e[i].N;
        int local = local0 - tab.e[i].t0;
        int nb = N >> 6;
        int n0 = (local % nb) * 64, k0 = (local / nb) * 64;
        #pragma unroll
        for (int r = 0; r < 4; ++r) {
            int k = r * 16 + (t >> 4);
            int n = (t & 15) * 4;
            float4 wv = *(const float4*)(W + (size_t)(k0 + k) * N + n0 + n);
            tile[k][n + 0] = f2bf(wv.x);
            tile[k][n + 1] = f2bf(wv.y);
            tile[k][n + 2] = f2bf(wv.z);
            tile[k][n + 3] = f2bf(wv.w);
        }
        __syncthreads();
        #pragma unroll
        for (int r = 0; r < 4; ++r) {
            int n = r * 16 + (t >> 4);
            int k = (t & 15) * 4;
            us4 o;
            o.x = tile[k + 0][n];
            o.y = tile[k + 1][n];
            o.z = tile[k + 2][n];
            o.w = tile[k + 3][n];
            *(us4*)(Wt + (size_t)(n0 + n) * K + k0 + k) = o;
        }
    } else {
        int blk2 = blk - 736;
        const float* gam; const float* bet; size_t ip;
        if (blk2 < 4096) {
            int b = blk2 >> 11;
            ip = ((size_t)b * ROWS_B + (blk2 & 2047)) * DIM + t;
            gam = g1; bet = b1;
        } else {
            int r2 = blk2 - 4096;
            int b = r2 >> 5;
            ip = ((size_t)b * ROWS_B + LS + (r2 & 31)) * DIM + t;
            gam = g3; bet = b3;
        }
        float v = latents[ip];
        float a = v, b2 = v * v;
        #pragma unroll
        for (int m = 32; m >= 1; m >>= 1) { a += __shfl_xor(a, m); b2 += __shfl_xor(b2, m); }
        if ((t & 63) == 0) { red[t >> 6] = a; red[4 + (t >> 6)] = b2; }
        __syncthreads();
        float mean = (red[0] + red[1] + red[2] + red[3]) * (1.0f / 256.0f);
        float var  = (red[4] + red[5] + red[6] + red[7]) * (1.0f / 256.0f) - mean * mean;
        float y = (v - mean) * rsqrtf(var + 1e-5f) * gam[t] + bet[t];
        if (blk2 < 4096) Xb[(size_t)blk2 * DIM + t] = f2bf(y);
        else             GQ[(size_t)(blk2 - 4096) * DIM + t] = y;
    }
}

// ---------------- plain LN (ln2), bf16 out ----------------
__global__ __launch_bounds__(256) void ln_rows_k(
    const float* __restrict__ in, const float* __restrict__ gam,
    const float* __restrict__ bet, unsigned short* __restrict__ out)
{
    __shared__ float red[8];
    int r = blockIdx.x, t = threadIdx.x;
    int b = r >> 11;
    size_t ip = ((size_t)b * ROWS_B + (r & 2047)) * DIM + t;
    float v = in[ip];
    float a = v, b2 = v * v;
    #pragma unroll
    for (int m = 32; m >= 1; m >>= 1) { a += __shfl_xor(a, m); b2 += __shfl_xor(b2, m); }
    if ((t & 63) == 0) { red[t >> 6] = a; red[4 + (t >> 6)] = b2; }
    __syncthreads();
    float mean = (red[0] + red[1] + red[2] + red[3]) * (1.0f / 256.0f);
    float var  = (red[4] + red[5] + red[6] + red[7]) * (1.0f / 256.0f) - mean * mean;
    out[(size_t)r * DIM + t] = f2bf((v - mean) * rsqrtf(var + 1e-5f) * gam[t] + bet[t]);
}

// ---------------- wgs: glob-score fold weights ----------------
__global__ __launch_bounds__(256) void wgs_k(
    const unsigned short* __restrict__ wtq, const unsigned short* __restrict__ kvglb,
    unsigned short* __restrict__ wgs)
{
    int n = blockIdx.x, k = threadIdx.x;
    int h = n & 7, cg = n >> 3;
    float acc = 0.0f;
    #pragma unroll
    for (int dd = 0; dd < 32; ++dd)
        acc += bf2f(wtq[(size_t)(h * 32 + dd) * 256 + k]) * bf2f(kvglb[(size_t)cg * 512 + h * 32 + dd]);
    wgs[(size_t)n * 256 + k] = f2bf(acc);
}

// ---------------- bf16 MFMA GEMM body (64x64 tile) ----------------
template<int BIAS, int DOGELU, int RES, int ABF16, int CBF16>
__device__ __forceinline__ void mgemm_body(
    const void* __restrict__ Av, const unsigned short* __restrict__ Bt,
    const float* __restrict__ bias, const float* __restrict__ Res,
    void* __restrict__ Cv, int N, int K, int bstr,
    int arpb, int absr, int aoff, int crpb, int cbsr, int coff,
    int col0, int row0)
{
    __shared__ unsigned short Asl[64][64];
    __shared__ unsigned short Bsl[64][64];
    int t = threadIdx.x;
    int lane = t & 63, w = t >> 6;
    int wr = w >> 1, wc = w & 1;
    int lrow = lane & 15, lk = lane >> 4;

    int srow = t >> 4;
    int scol = (t & 15) << 2;
    int sslot = (t & 15) >> 1;
    int shalf = (t & 15) & 1;

    f32x4 acc[2][2];
    #pragma unroll
    for (int m = 0; m < 2; ++m)
        #pragma unroll
        for (int n = 0; n < 2; ++n)
            acc[m][n] = (f32x4){0.f, 0.f, 0.f, 0.f};

    for (int kk = 0; kk < K; kk += 64) {
        #pragma unroll
        for (int r = 0; r < 4; ++r) {
            int row = r * 16 + srow;
            int ar = row0 + row;
            size_t ab = ((size_t)(ar / arpb) * absr + aoff + (ar % arpb)) * (size_t)K + kk + scol;
            us4 ap;
            if (ABF16) {
                ap = *(const us4*)((const unsigned short*)Av + ab);
            } else {
                float4 av = *(const float4*)((const float*)Av + ab);
                ap.x = f2bf(av.x); ap.y = f2bf(av.y); ap.z = f2bf(av.z); ap.w = f2bf(av.w);
            }
            *(us4*)&Asl[row][((sslot ^ (row & 7)) << 3) + (shalf << 2)] = ap;
            us4 bv = *(const us4*)(Bt + (size_t)(col0 + row) * bstr + kk + scol);
            *(us4*)&Bsl[row][((sslot ^ (row & 7)) << 3) + (shalf << 2)] = bv;
        }
        __syncthreads();
        #pragma unroll
        for (int k2 = 0; k2 < 2; ++k2) {
            short8 af[2], bfr[2];
            #pragma unroll
            for (int m = 0; m < 2; ++m) {
                int rowA = wr * 32 + m * 16 + lrow;
                af[m] = *(short8*)&Asl[rowA][((k2 * 4 + lk) ^ (rowA & 7)) << 3];
                int rowB = wc * 32 + m * 16 + lrow;
                bfr[m] = *(short8*)&Bsl[rowB][((k2 * 4 + lk) ^ (rowB & 7)) << 3];
            }
            #pragma unroll
            for (int m = 0; m < 2; ++m)
                #pragma unroll
                for (int n = 0; n < 2; ++n)
                    acc[m][n] = __builtin_amdgcn_mfma_f32_16x16x32_bf16(af[m], bfr[n], acc[m][n], 0, 0, 0);
        }
        __syncthreads();
    }
    #pragma unroll
    for (int m = 0; m < 2; ++m) {
        #pragma unroll
        for (int n = 0; n < 2; ++n) {
            int col = col0 + wc * 32 + n * 16 + lrow;
            #pragma unroll
            for (int j = 0; j < 4; ++j) {
                int r = row0 + wr * 32 + m * 16 + lk * 4 + j;
                size_t cp = ((size_t)(r / crpb) * cbsr + coff + (r % crpb)) * (size_t)N + col;
                float o = acc[m][n][j];
                if (BIAS)   o += bias[col];
                if (DOGELU) o = gelu_f(o);
                if (RES)    o += Res[cp];
                if (CBF16) ((unsigned short*)Cv)[cp] = f2bf(o);
                else       ((float*)Cv)[cp] = o;
            }
        }
    }
}

template<int BIAS, int DOGELU, int RES, int ABF16, int CBF16>
__global__ __launch_bounds__(256) void mgemm_k(
    const void* __restrict__ Av, const unsigned short* __restrict__ Bt,
    const float* __restrict__ bias, const float* __restrict__ Res,
    void* __restrict__ Cv, int M, int N, int K, int bstr,
    int arpb, int absr, int aoff, int crpb, int cbsr, int coff)
{
    mgemm_body<BIAS, DOGELU, RES, ABF16, CBF16>(
        Av, Bt, bias, Res, Cv, N, K, bstr, arpb, absr, aoff, crpb, cbsr, coff,
        blockIdx.x * 64, blockIdx.y * 64);
}

// ---------------- merged KVG (x<8) + GKVQ (x>=8, y==0) projections ----------------
__global__ __launch_bounds__(256) void kvg_pair_k(
    const float* __restrict__ outp, const float* __restrict__ GQ,
    const unsigned short* __restrict__ wt_gakv,
    unsigned short* __restrict__ KVGb, unsigned short* __restrict__ GKVQb)
{
    int x = blockIdx.x, y = blockIdx.y;
    if (x < 8) {
        // KVG: [4096][512] = out(spatial view) @ gakv[0:512]
        mgemm_body<0,0,0,0,1>(outp, wt_gakv, nullptr, nullptr, KVGb,
            512, 256, 256, LS, ROWS_B, 0, 4096, 4096, 0, x * 64, y * 64);
    } else {
        if (y != 0) return;
        // GKVQ: [64][768] = GQ @ gakv[0:768]
        mgemm_body<0,0,0,0,1>(GQ, wt_gakv, nullptr, nullptr, GKVQb,
            768, 256, 256, 64, 64, 0, 64, 64, 0, (x - 8) * 64, 0);
    }
}

// ---------------- fused spatial attention (QKV2 stride 1536, GS inline at +1024) ----------------
__global__ __launch_bounds__(256) void attn_sp_k(
    const unsigned short* __restrict__ QKV, const unsigned short* __restrict__ KVGLb,
    const int* __restrict__ idx, const float* __restrict__ rpe,
    const float* __restrict__ srpe, const float* __restrict__ dist,
    const float* __restrict__ lsig, const float* __restrict__ gbias,
    unsigned short* __restrict__ ORb)
{
    __shared__ float s_rpe[17 * 32];
    __shared__ float s_sc[NCTX * 8];
    __shared__ float s_red[32 * 64];
    __shared__ float s_d[16];
    __shared__ int   s_row[17];
    int t = threadIdx.x;
    int r = blockIdx.x;
    int b = r >> 11;
    int w = t >> 6, lane = t & 63;
    int h = lane >> 3, dg = lane & 7;

    if (t < 32) s_rpe[t] = srpe[(size_t)r * 32 + t];
    for (int i = t; i < 512; i += 256) s_rpe[32 + i] = rpe[(size_t)r * 512 + i];
    if (t < 16) {
        s_row[t + 1] = (b << 11) + idx[r * 16 + t];
        s_d[t] = dist[(size_t)r * 16 + t];
    }
    if (t == 16) s_row[0] = r;

    size_t qb = (size_t)r * QSTR + lane * 4;
    float4 q4  = bf2f4(*(const us4*)(QKV + qb));
    float4 qw4 = bf2f4(*(const us4*)(QKV + qb + 768));
    float inv2s = 1.0f / (2.0f * __expf(2.0f * lsig[h]));
    float gb = gbias[0];
    __syncthreads();

    us4 kreg[5];
    #pragma unroll
    for (int i = 0; i < 5; ++i) {
        int c = w + 4 * i;
        if (c < 17) kreg[i] = *(const us4*)(QKV + (size_t)s_row[c] * QSTR + 256 + lane * 4);
    }
    float sc_loc[5];
    #pragma unroll
    for (int i = 0; i < 5; ++i) {
        int c = w + 4 * i;
        if (c < 17) {
            float4 k4 = bf2f4(kreg[i]);
            float4 rv4 = *(const float4*)&s_rpe[c * 32 + dg * 4];
            float part = dot4(q4, k4) + dot4(rv4, qw4);
            part += __shfl_xor(part, 1);
            part += __shfl_xor(part, 2);
            part += __shfl_xor(part, 4);
            float bia = (c == 0) ? 0.0f : -s_d[c - 1] * s_d[c - 1] * inv2s;
            float sval = part * SCALE + bia;
            if (dg == 0) s_sc[c * 8 + h] = sval;
            sc_loc[i] = sval;
        }
    }
    float sc_glob[8];
    #pragma unroll
    for (int i = 0; i < 8; ++i) {
        int gi = w + 4 * i;
        float sval = bf2f(QKV[(size_t)r * QSTR + 1024 + (((size_t)b * 32 + gi) << 3) + h]) * SCALE + gb;
        if (dg == 0) s_sc[(17 + gi) * 8 + h] = sval;
        sc_glob[i] = sval;
    }
    __syncthreads();

    float vals[7];
    float lm = -3.0e38f;
    #pragma unroll
    for (int i = 0; i < 7; ++i) {
        int cc = dg + 8 * i;
        if (cc < NCTX) { float v = s_sc[cc * 8 + h]; vals[i] = v; lm = fmaxf(lm, v); }
    }
    lm = fmaxf(lm, __shfl_xor(lm, 1));
    lm = fmaxf(lm, __shfl_xor(lm, 2));
    lm = fmaxf(lm, __shfl_xor(lm, 4));
    float ls = 0.0f;
    #pragma unroll
    for (int i = 0; i < 7; ++i) {
        int cc = dg + 8 * i;
        if (cc < NCTX) ls += __expf(vals[i] - lm);
    }
    ls += __shfl_xor(ls, 1);
    ls += __shfl_xor(ls, 2);
    ls += __shfl_xor(ls, 4);
    float inv = 1.0f / ls;

    us4 vreg[5];
    #pragma unroll
    for (int i = 0; i < 5; ++i) {
        int c = w + 4 * i;
        if (c < 17) vreg[i] = *(const us4*)(QKV + (size_t)s_row[c] * QSTR + 512 + lane * 4);
    }
    float4 acc4 = (float4){0, 0, 0, 0}, racc4 = (float4){0, 0, 0, 0};
    #pragma unroll
    for (int i = 0; i < 5; ++i) {
        int c = w + 4 * i;
        if (c < 17) {
            float p = __expf(sc_loc[i] - lm);
            float4 v4 = bf2f4(vreg[i]);
            float4 rv4 = *(const float4*)&s_rpe[c * 32 + dg * 4];
            racc4.x += p * rv4.x; racc4.y += p * rv4.y;
            racc4.z += p * rv4.z; racc4.w += p * rv4.w;
            acc4.x += p * v4.x; acc4.y += p * v4.y;
            acc4.z += p * v4.z; acc4.w += p * v4.w;
        }
    }
    #pragma unroll
    for (int i = 0; i < 8; ++i) {
        int gi = w + 4 * i;
        float p = __expf(sc_glob[i] - lm);
        float4 v4 = bf2f4(*(const us4*)(KVGLb + ((size_t)(b * NG + gi)) * 512 + 256 + lane * 4));
        acc4.x += p * v4.x; acc4.y += p * v4.y;
        acc4.z += p * v4.z; acc4.w += p * v4.w;
    }

    s_red[(w * 8 + 0) * 64 + lane] = acc4.x;
    s_red[(w * 8 + 1) * 64 + lane] = acc4.y;
    s_red[(w * 8 + 2) * 64 + lane] = acc4.z;
    s_red[(w * 8 + 3) * 64 + lane] = acc4.w;
    s_red[(w * 8 + 4) * 64 + lane] = racc4.x;
    s_red[(w * 8 + 5) * 64 + lane] = racc4.y;
    s_red[(w * 8 + 6) * 64 + lane] = racc4.z;
    s_red[(w * 8 + 7) * 64 + lane] = racc4.w;
    __syncthreads();
    {
        int j = w;
        float a = 0.0f, rr = 0.0f;
        #pragma unroll
        for (int ww = 0; ww < 4; ++ww) {
            a  += s_red[(ww * 8 + j) * 64 + lane];
            rr += s_red[(ww * 8 + 4 + j) * 64 + lane];
        }
        int e = h * 32 + dg * 4 + j;
        ORb[(size_t)r * 512 + e]       = f2bf(a * inv);
        ORb[(size_t)r * 512 + 256 + e] = f2bf(rr * inv);
    }
}

// ---------------- global attention: scores via MFMA ----------------
__global__ __launch_bounds__(256) void ga_scores_k(
    const unsigned short* __restrict__ GKVQ, const unsigned short* __restrict__ KVG,
    float* __restrict__ A2)
{
    int t = threadIdx.x;
    int bh = blockIdx.x;
    int b = bh >> 3, h = bh & 7;
    int w = t >> 6, lane = t & 63;
    int ct = blockIdx.y * 4 + w;
    if (ct >= 130) return;
    int lr = lane & 15, lq = lane >> 4;

    short8 aq0 = *(const short8*)(GKVQ + ((size_t)(b * 32 + lr)) * 768 + 512 + h * 32 + lq * 8);
    short8 aq1 = *(const short8*)(GKVQ + ((size_t)(b * 32 + 16 + lr)) * 768 + 512 + h * 32 + lq * 8);
    int c = ct * 16 + lr;
    const unsigned short* kr = (c < LS)
        ? KVG + ((size_t)(b * LS + c)) * 512 + h * 32 + lq * 8
        : GKVQ + ((size_t)(b * NG + (c - LS))) * 768 + h * 32 + lq * 8;
    short8 bk = *(const short8*)kr;

    f32x4 acc0 = (f32x4){0, 0, 0, 0}, acc1 = (f32x4){0, 0, 0, 0};
    acc0 = __builtin_amdgcn_mfma_f32_16x16x32_bf16(aq0, bk, acc0, 0, 0, 0);
    acc1 = __builtin_amdgcn_mfma_f32_16x16x32_bf16(aq1, bk, acc1, 0, 0, 0);

    float* arow = A2 + ((size_t)(b * NH + h) * NG) * ROWS_B + ct * 16 + lr;
    #pragma unroll
    for (int j = 0; j < 4; ++j) {
        arow[(size_t)(lq * 4 + j) * ROWS_B]        = acc0[j] * SCALE;
        arow[(size_t)(16 + lq * 4 + j) * ROWS_B]   = acc1[j] * SCALE;
    }
}

// ---------------- global attention: row softmax over 2080 ----------------
__global__ __launch_bounds__(256) void ga_softmax_k(float* __restrict__ A2)
{
    __shared__ float red[8];
    int t = threadIdx.x;
    float* row = A2 + (size_t)blockIdx.x * ROWS_B;
    float lm = -1e30f;
    for (int i = t; i < ROWS_B; i += 256) lm = fmaxf(lm, row[i]);
    #pragma unroll
    for (int m = 32; m >= 1; m >>= 1) lm = fmaxf(lm, __shfl_xor(lm, m));
    if ((t & 63) == 0) red[t >> 6] = lm;
    __syncthreads();
    float M = fmaxf(fmaxf(red[0], red[1]), fmaxf(red[2], red[3]));
    float ls = 0.0f;
    for (int i = t; i < ROWS_B; i += 256) {
        float e = __expf(row[i] - M);
        row[i] = e;
        ls += e;
    }
    #pragma unroll
    for (int m = 32; m >= 1; m >>= 1) ls += __shfl_xor(ls, m);
    if ((t & 63) == 0) red[4 + (t >> 6)] = ls;
    __syncthreads();
    float inv = 1.0f / (red[4] + red[5] + red[6] + red[7]);
    for (int i = t; i < ROWS_B; i += 256) row[i] *= inv;
}

// ---------------- global attention: weighted V (32-way split-K, bf16) ----------------
__global__ __launch_bounds__(256) void ga_wv_k(
    const float* __restrict__ A2, const unsigned short* __restrict__ GKVQ,
    const unsigned short* __restrict__ KVG, float* __restrict__ OGP)
{
    __shared__ float s_acc[8][256];
    int t = threadIdx.x;
    int bg = blockIdx.x;       // b*32+g
    int s = blockIdx.y;        // 0..31
    int b = bg >> 5, g = bg & 31;
    int tt = t & 31, sub = t >> 5;
    int h = tt >> 2;
    const float* w = A2 + ((size_t)(b * NH + h) * NG + g) * ROWS_B;
    int c0 = s * 65, cend = c0 + 65;
    float acc[8] = {};
    for (int c = c0 + sub; c < cend; c += 8) {
        float p = w[c];
        const unsigned short* vr = (c < LS)
            ? KVG + ((size_t)(b * LS + c)) * 512 + 256 + tt * 8
            : GKVQ + ((size_t)(b * NG + (c - LS))) * 768 + 256 + tt * 8;
        us4 v0 = *(const us4*)vr;
        us4 v1 = *(const us4*)(vr + 4);
        acc[0] += p * bf2f(v0.x); acc[1] += p * bf2f(v0.y);
        acc[2] += p * bf2f(v0.z); acc[3] += p * bf2f(v0.w);
        acc[4] += p * bf2f(v1.x); acc[5] += p * bf2f(v1.y);
        acc[6] += p * bf2f(v1.z); acc[7] += p * bf2f(v1.w);
    }
    #pragma unroll
    for (int j = 0; j < 8; ++j) s_acc[sub][tt * 8 + j] = acc[j];
    __syncthreads();
    float o = 0.0f;
    #pragma unroll
    for (int ss = 0; ss < 8; ++ss) o += s_acc[ss][t];
    OGP[((size_t)bg * 32 + s) * 256 + t] = o;
}

// ---------------- glob tail, 4 blocks per row ----------------
__global__ __launch_bounds__(1024) void glob_tail_k(
    const float* __restrict__ OGP, const float* __restrict__ latents,
    const float* __restrict__ ga_wo, const float* __restrict__ ga_bo,
    const float* __restrict__ ln4g, const float* __restrict__ ln4b,
    const float* __restrict__ w1, const float* __restrict__ b1,
    const float* __restrict__ w2, const float* __restrict__ b2,
    float* __restrict__ GTP)
{
    __shared__ float s_part[4][256];
    __shared__ float s_og[256];
    __shared__ float s_y[256];
    __shared__ float s_h1[256];
    __shared__ float red[16];
    int bg = blockIdx.x, q = blockIdx.y, t = threadIdx.x;
    int tt = t & 255, grp = t >> 8;

    float og = 0.0f;
    #pragma unroll
    for (int s = 0; s < 8; ++s)
        og += OGP[((size_t)bg * 32 + grp * 8 + s) * 256 + tt];
    s_part[grp][tt] = og;
    __syncthreads();
    if (grp == 0) s_og[tt] = s_part[0][tt] + s_part[1][tt] + s_part[2][tt] + s_part[3][tt];
    __syncthreads();

    float x = 0.0f;
    {
        int k0 = grp * 64;
        #pragma unroll 16
        for (int k = k0; k < k0 + 64; ++k) x += s_og[k] * ga_wo[(size_t)k * 256 + tt];
    }
    s_part[grp][tt] = x;
    __syncthreads();
    int b = bg >> 5;
    size_t row = (size_t)b * ROWS_B + LS + (bg & 31);
    float res = latents[row * 256 + tt]
              + s_part[0][tt] + s_part[1][tt] + s_part[2][tt] + s_part[3][tt] + ga_bo[tt];

    float a = res, b2s = res * res;
    #pragma unroll
    for (int m = 32; m >= 1; m >>= 1) { a += __shfl_xor(a, m); b2s += __shfl_xor(b2s, m); }
    if ((t & 63) == 0 && t < 256) { red[t >> 6] = a; red[8 + (t >> 6)] = b2s; }
    __syncthreads();
    float mean = (red[0] + red[1] + red[2] + red[3]) * (1.0f / 256.0f);
    float var  = (red[8] + red[9] + red[10] + red[11]) * (1.0f / 256.0f) - mean * mean;
    float y = (res - mean) * rsqrtf(var + 1e-5f) * ln4g[tt] + ln4b[tt];
    if (grp == 0) s_y[tt] = y;
    __syncthreads();

    float h1p = 0.0f;
    {
        int k0 = grp * 64;
        #pragma unroll 16
        for (int k = k0; k < k0 + 64; ++k) h1p += s_y[k] * w1[(size_t)k * 1024 + q * 256 + tt];
    }
    s_part[grp][tt] = h1p;
    __syncthreads();
    if (grp == 0)
        s_h1[tt] = gelu_f(b1[q * 256 + tt]
                 + s_part[0][tt] + s_part[1][tt] + s_part[2][tt] + s_part[3][tt]);
    __syncthreads();

    float o = 0.0f;
    {
        int j0 = grp * 64;
        #pragma unroll 16
        for (int j = j0; j < j0 + 64; ++j) o += s_h1[j] * w2[(size_t)(q * 256 + j) * 256 + tt];
    }
    s_part[grp][tt] = o;
    __syncthreads();
    if (grp == 0) {
        float v = s_part[0][tt] + s_part[1][tt] + s_part[2][tt] + s_part[3][tt];
        if (q == 0) v += res + b2[tt];
        GTP[((size_t)bg * 4 + q) * 256 + tt] = v;
    }
}

__global__ __launch_bounds__(256) void glob_fin_k(
    const float* __restrict__ GTP, float* __restrict__ out)
{
    int bg = blockIdx.x, t = threadIdx.x;
    int b = bg >> 5;
    size_t row = (size_t)b * ROWS_B + LS + (bg & 31);
    float v = GTP[((size_t)bg * 4 + 0) * 256 + t] + GTP[((size_t)bg * 4 + 1) * 256 + t]
            + GTP[((size_t)bg * 4 + 2) * 256 + t] + GTP[((size_t)bg * 4 + 3) * 256 + t];
    out[row * 256 + t] = v;
}

// ---------------- launch ----------------
extern "C" void kernel_launch(void* const* d_in, const int* in_sizes, int n_in,
                              void* d_out, int out_size, void* d_ws, size_t ws_size,
                              hipStream_t stream)
{
    const float* latents = (const float*)d_in[0];
    const int*   idx     = (const int*)d_in[1];
    const float* rpe     = (const float*)d_in[2];
    const float* srpe    = (const float*)d_in[3];
    const float* dist    = (const float*)d_in[4];
    const float* sa_wq   = (const float*)d_in[6];
    const float* sa_wk   = (const float*)d_in[7];
    const float* sa_wv   = (const float*)d_in[8];
    const float* sa_wo   = (const float*)d_in[9];
    const float* sa_bo   = (const float*)d_in[10];
    const float* lsig    = (const float*)d_in[11];
    const float* gbias   = (const float*)d_in[12];
    const float* ln1g    = (const float*)d_in[13];
    const float* ln1b    = (const float*)d_in[14];
    const float* ln2g    = (const float*)d_in[15];
    const float* ln2b    = (const float*)d_in[16];
    const float* sff_w1  = (const float*)d_in[17];
    const float* sff_b1  = (const float*)d_in[18];
    const float* sff_w2  = (const float*)d_in[19];
    const float* sff_b2  = (const float*)d_in[20];
    const float* ga_wq   = (const float*)d_in[21];
    const float* ga_wk   = (const float*)d_in[22];
    const float* ga_wv   = (const float*)d_in[23];
    const float* ga_wo   = (const float*)d_in[24];
    const float* ga_bo   = (const float*)d_in[25];
    const float* ln3g    = (const float*)d_in[27];
    const float* ln3b    = (const float*)d_in[28];
    const float* ln4g    = (const float*)d_in[29];
    const float* ln4b    = (const float*)d_in[30];
    const float* gff_w1  = (const float*)d_in[31];
    const float* gff_b1  = (const float*)d_in[32];
    const float* gff_w2  = (const float*)d_in[33];
    const float* gff_b2  = (const float*)d_in[34];
    float* out = (float*)d_out;

    const size_t SZ = (size_t)4096 * 256;
    float* ws = (float*)d_ws;
    unsigned short* Xb = (unsigned short*)ws;              // [0, SZ/2 f32) bf16 [4096][256]
    unsigned short* QKV2b = (unsigned short*)(ws + SZ);    // [SZ,4SZ) bf16 [4096][1536]
    unsigned short* H1b  = QKV2b;                          // overlays after attn
    unsigned short* KVGb = QKV2b;                          // overlays after ff2
    unsigned short* ORb  = (unsigned short*)(ws + 4 * SZ); // bf16 [4096][512]
    float* A2  = ws + 5 * SZ;
    float* OGP = A2 + (size_t)2 * NH * NG * ROWS_B;        // [64*32][256]
    float* GTP = OGP + (size_t)64 * 32 * 256;              // [64*4][256]
    unsigned short* wt = (unsigned short*)(ws + 7 * SZ);
    unsigned short* wt_qkvw = wt;                          // [1024][256]
    unsigned short* wgs_w   = wt + 262144;                 // [512][256] (contiguous -> N=1536)
    unsigned short* wt_ff1  = wt + 393216;                 // [1024][256]
    unsigned short* wt_ff2  = wt + 655360;                 // [256][1024]
    unsigned short* wt_gakv = wt + 917504;                 // [768][256]
    unsigned short* wt_wo2  = wt + 1114112;                // [256][512]
    float* smalls = ws + 8 * SZ;
    unsigned short* KVGLb = (unsigned short*)smalls;       // bf16 [64][512]
    float* GQ = smalls + 16384;                            // f32 [64][256]
    unsigned short* GKVQb = (unsigned short*)(GQ + 16384); // bf16 [64][768]

    dim3 blk(256);

    WTab tab;
    tab.e[0] = { sa_wq,  wt_qkvw,           256,  256,   0 };
    tab.e[1] = { sa_wk,  wt_qkvw + 65536,   256,  256,  16 };
    tab.e[2] = { sa_wv,  wt_qkvw + 131072,  256,  256,  32 };
    tab.e[3] = { sff_w1, wt_ff1,            256, 1024,  48 };
    tab.e[4] = { sff_w2, wt_ff2,           1024,  256, 112 };
    tab.e[5] = { ga_wk,  wt_gakv,           256,  256, 176 };
    tab.e[6] = { ga_wv,  wt_gakv + 65536,   256,  256, 192 };
    tab.e[7] = { ga_wq,  wt_gakv + 131072,  256,  256, 208 };
    tab.e[8] = { sa_wq,  wt_qkvw,           256,  256, 1 << 30 };

    // merged prep: wspecial + wconv + ln1/ln3 (X bf16)
    wprep_k<<<dim3(4896), blk, 0, stream>>>(tab, sa_wq, sa_wk, sa_wv, sa_wo,
                                            wt_qkvw, wt_wo2, latents,
                                            ln1g, ln1b, ln3g, ln3b, Xb, GQ);

    // spatial-attn glob K|V (bf16), then glob-score fold weights
    mgemm_k<0,0,0,0,1><<<dim3(8,1), blk, 0, stream>>>(latents, wt_qkvw + 65536, nullptr, nullptr, KVGLb,
        64,512,256,256, 32,ROWS_B,LS, 64,64,0);
    wgs_k<<<dim3(512), blk, 0, stream>>>(wt_qkvw, KVGLb, wgs_w);

    // QKV + qw + glob-scores in ONE GEMM (N=1536, A bf16)
    mgemm_k<0,0,0,1,1><<<dim3(24,64), blk, 0, stream>>>(Xb, wt_qkvw, nullptr, nullptr, QKV2b,
        4096,QSTR,256,256, 4096,4096,0, 4096,4096,0);

    // fused spatial attention -> ORb = [O_base | R] (bf16)
    attn_sp_k<<<dim3(4096), blk, 0, stream>>>(QKV2b, KVGLb, idx, rpe, srpe, dist,
                                              lsig, gbias, ORb);

    // spatial residual: out = latents + ORb @ [Wo;Wvo] + bo
    mgemm_k<1,0,1,1,0><<<dim3(4,64), blk, 0, stream>>>(ORb, wt_wo2, sa_bo, latents, out,
        4096,256,512,512, 4096,4096,0, LS,ROWS_B,0);

    // spatial FF (X bf16)
    ln_rows_k<<<dim3(4096), blk, 0, stream>>>(out, ln2g, ln2b, Xb);
    mgemm_k<1,1,0,1,1><<<dim3(16,64), blk, 0, stream>>>(Xb, wt_ff1, sff_b1, nullptr, H1b,
        4096,1024,256,256, 4096,4096,0, 4096,4096,0);
    mgemm_k<1,0,1,1,0><<<dim3(4,64), blk, 0, stream>>>(H1b, wt_ff2, sff_b2, out, out,
        4096,256,1024,1024, 4096,4096,0, LS,ROWS_B,0);

    // merged global-attention projections: KVG (x<8) + GKVQ (x>=8, y==0)
    kvg_pair_k<<<dim3(20,64), blk, 0, stream>>>(out, GQ, wt_gakv, KVGb, GKVQb);

    // global attention
    ga_scores_k<<<dim3(16, 33), blk, 0, stream>>>(GKVQb, KVGb, A2);
    ga_softmax_k<<<dim3(512), blk, 0, stream>>>(A2);
    ga_wv_k<<<dim3(64, 32), blk, 0, stream>>>(A2, GKVQb, KVGb, OGP);

    // glob tail: 4-way sliced + final combine
    glob_tail_k<<<dim3(64, 4), dim3(1024), 0, stream>>>(OGP, latents, ga_wo, ga_bo, ln4g, ln4b,
                                                        gff_w1, gff_b1, gff_w2, gff_b2, GTP);
    glob_fin_k<<<dim3(64), blk, 0, stream>>>(GTP, out);
}

// Round 15
// 136.797 us; speedup vs baseline: 1.3330x; 1.0220x over previous
//
#include <hip/hip_runtime.h>
#include <math.h>

// B=2, LS=2048, G=32, KNN=16, DIM=256, PE=32, H=8, DH=32, INNER=256, FF=1024
#define LS 2048
#define NG 32
#define ROWS_B 2080
#define DIM 256
#define PE 32
#define NH 8
#define DH 32
#define NCTX 49
#define SCALE 0.17677669529663687f  // 1/sqrt(32)
#define QSTR 1536                   // QKV2 row stride: q|k|v|qw|gs

typedef __attribute__((ext_vector_type(8))) short short8;
typedef __attribute__((ext_vector_type(4))) float f32x4;
typedef __attribute__((ext_vector_type(4))) unsigned short us4;

__device__ __forceinline__ unsigned short f2bf(float x)
{
    unsigned int u = __float_as_uint(x);
    unsigned int r = (u + 0x7fffu + ((u >> 16) & 1u)) >> 16;
    return (unsigned short)r;
}
__device__ __forceinline__ float bf2f(unsigned short v)
{
    return __uint_as_float((unsigned int)v << 16);
}
__device__ __forceinline__ float4 bf2f4(us4 v)
{
    return (float4){ bf2f(v.x), bf2f(v.y), bf2f(v.z), bf2f(v.w) };
}
__device__ __forceinline__ float dot4(float4 a, float4 b)
{
    return a.x * b.x + a.y * b.y + a.z * b.z + a.w * b.w;
}
__device__ __forceinline__ float gelu_f(float x)
{
    float x3 = x * x * x;
    return 0.5f * x * (1.0f + tanhf(0.7978845608028654f * (x + 0.044715f * x3)));
}

struct WEnt { const float* src; unsigned short* dst; int K; int N; int t0; };
struct WTab { WEnt e[9]; };

// ---------------- merged prep: wspecial (512) + wconv (224) + ln1/ln3 (4160) ----------------
__global__ __launch_bounds__(256) void wprep_k(
    WTab tab,
    const float* __restrict__ sa_wq, const float* __restrict__ sa_wk,
    const float* __restrict__ sa_wv, const float* __restrict__ sa_wo,
    unsigned short* __restrict__ wt_qkvw, unsigned short* __restrict__ wt_wo2,
    const float* __restrict__ latents,
    const float* __restrict__ g1, const float* __restrict__ b1,
    const float* __restrict__ g3, const float* __restrict__ b3,
    unsigned short* __restrict__ Xb, float* __restrict__ GQ)
{
    __shared__ unsigned short tile[64][72];
    __shared__ float red[8];
    int blk = blockIdx.x, t = threadIdx.x;
    if (blk < 512) {
        const float* wkpe = sa_wk + 256 * 256;
        const float* wvpe = sa_wv + 256 * 256;
        if (blk < 256) {
            int j = blk, h = j >> 5, p = j & 31;
            const float* wq = sa_wq + (size_t)t * 256 + h * 32;
            const float* wk = wkpe + (size_t)p * 256 + h * 32;
            float acc = 0.0f;
            #pragma unroll
            for (int dd = 0; dd < 32; ++dd) acc += wq[dd] * wk[dd];
            wt_qkvw[(size_t)(768 + j) * 256 + t] = f2bf(acc);
        } else {
            int n = blk - 256;
            #pragma unroll
            for (int kk = 0; kk < 2; ++kk) {
                int k = t + kk * 256;
                float v;
                if (k < 256) v = sa_wo[(size_t)k * 256 + n];
                else {
                    int j = k - 256, h = j >> 5, p = j & 31;
                    float a = 0.0f;
                    #pragma unroll
                    for (int dd = 0; dd < 32; ++dd)
                        a += wvpe[(size_t)p * 256 + h * 32 + dd] * sa_wo[(size_t)(h * 32 + dd) * 256 + n];
                    v = a;
                }
                wt_wo2[(size_t)n * 512 + k] = f2bf(v);
            }
        }
    } else if (blk < 736) {
        int local0 = blk - 512;
        int i = 0;
        #pragma unroll
        for (int j = 1; j < 9; ++j) if (local0 >= tab.e[j].t0) i = j;
        const float* W = tab.e[i].src;
        unsigned short* Wt = tab.e[i].dst;
        int K = tab.e[i].K, N = tab.e[i].N;
        int local = local0 - tab.e[i].t0;
        int nb = N >> 6;
        int n0 = (local % nb) * 64, k0 = (local / nb) * 64;
        #pragma unroll
        for (int r = 0; r < 4; ++r) {
            int k = r * 16 + (t >> 4);
            int n = (t & 15) * 4;
            float4 wv = *(const float4*)(W + (size_t)(k0 + k) * N + n0 + n);
            tile[k][n + 0] = f2bf(wv.x);
            tile[k][n + 1] = f2bf(wv.y);
            tile[k][n + 2] = f2bf(wv.z);
            tile[k][n + 3] = f2bf(wv.w);
        }
        __syncthreads();
        #pragma unroll
        for (int r = 0; r < 4; ++r) {
            int n = r * 16 + (t >> 4);
            int k = (t & 15) * 4;
            us4 o;
            o.x = tile[k + 0][n];
            o.y = tile[k + 1][n];
            o.z = tile[k + 2][n];
            o.w = tile[k + 3][n];
            *(us4*)(Wt + (size_t)(n0 + n) * K + k0 + k) = o;
        }
    } else {
        int blk2 = blk - 736;
        const float* gam; const float* bet; size_t ip;
        if (blk2 < 4096) {
            int b = blk2 >> 11;
            ip = ((size_t)b * ROWS_B + (blk2 & 2047)) * DIM + t;
            gam = g1; bet = b1;
        } else {
            int r2 = blk2 - 4096;
            int b = r2 >> 5;
            ip = ((size_t)b * ROWS_B + LS + (r2 & 31)) * DIM + t;
            gam = g3; bet = b3;
        }
        float v = latents[ip];
        float a = v, b2 = v * v;
        #pragma unroll
        for (int m = 32; m >= 1; m >>= 1) { a += __shfl_xor(a, m); b2 += __shfl_xor(b2, m); }
        if ((t & 63) == 0) { red[t >> 6] = a; red[4 + (t >> 6)] = b2; }
        __syncthreads();
        float mean = (red[0] + red[1] + red[2] + red[3]) * (1.0f / 256.0f);
        float var  = (red[4] + red[5] + red[6] + red[7]) * (1.0f / 256.0f) - mean * mean;
        float y = (v - mean) * rsqrtf(var + 1e-5f) * gam[t] + bet[t];
        if (blk2 < 4096) Xb[(size_t)blk2 * DIM + t] = f2bf(y);
        else             GQ[(size_t)(blk2 - 4096) * DIM + t] = y;
    }
}

// ---------------- plain LN (ln2), bf16 out ----------------
__global__ __launch_bounds__(256) void ln_rows_k(
    const float* __restrict__ in, const float* __restrict__ gam,
    const float* __restrict__ bet, unsigned short* __restrict__ out)
{
    __shared__ float red[8];
    int r = blockIdx.x, t = threadIdx.x;
    int b = r >> 11;
    size_t ip = ((size_t)b * ROWS_B + (r & 2047)) * DIM + t;
    float v = in[ip];
    float a = v, b2 = v * v;
    #pragma unroll
    for (int m = 32; m >= 1; m >>= 1) { a += __shfl_xor(a, m); b2 += __shfl_xor(b2, m); }
    if ((t & 63) == 0) { red[t >> 6] = a; red[4 + (t >> 6)] = b2; }
    __syncthreads();
    float mean = (red[0] + red[1] + red[2] + red[3]) * (1.0f / 256.0f);
    float var  = (red[4] + red[5] + red[6] + red[7]) * (1.0f / 256.0f) - mean * mean;
    out[(size_t)r * DIM + t] = f2bf((v - mean) * rsqrtf(var + 1e-5f) * gam[t] + bet[t]);
}

// ---------------- wgs: glob-score fold weights ----------------
__global__ __launch_bounds__(256) void wgs_k(
    const unsigned short* __restrict__ wtq, const unsigned short* __restrict__ kvglb,
    unsigned short* __restrict__ wgs)
{
    int n = blockIdx.x, k = threadIdx.x;
    int h = n & 7, cg = n >> 3;
    float acc = 0.0f;
    #pragma unroll
    for (int dd = 0; dd < 32; ++dd)
        acc += bf2f(wtq[(size_t)(h * 32 + dd) * 256 + k]) * bf2f(kvglb[(size_t)cg * 512 + h * 32 + dd]);
    wgs[(size_t)n * 256 + k] = f2bf(acc);
}

// ---------------- bf16 MFMA GEMM body (64x64 tile) ----------------
template<int BIAS, int DOGELU, int RES, int ABF16, int CBF16>
__device__ __forceinline__ void mgemm_body(
    const void* __restrict__ Av, const unsigned short* __restrict__ Bt,
    const float* __restrict__ bias, const float* __restrict__ Res,
    void* __restrict__ Cv, int N, int K, int bstr,
    int arpb, int absr, int aoff, int crpb, int cbsr, int coff,
    int col0, int row0)
{
    __shared__ unsigned short Asl[64][64];
    __shared__ unsigned short Bsl[64][64];
    int t = threadIdx.x;
    int lane = t & 63, w = t >> 6;
    int wr = w >> 1, wc = w & 1;
    int lrow = lane & 15, lk = lane >> 4;

    int srow = t >> 4;
    int scol = (t & 15) << 2;
    int sslot = (t & 15) >> 1;
    int shalf = (t & 15) & 1;

    f32x4 acc[2][2];
    #pragma unroll
    for (int m = 0; m < 2; ++m)
        #pragma unroll
        for (int n = 0; n < 2; ++n)
            acc[m][n] = (f32x4){0.f, 0.f, 0.f, 0.f};

    for (int kk = 0; kk < K; kk += 64) {
        #pragma unroll
        for (int r = 0; r < 4; ++r) {
            int row = r * 16 + srow;
            int ar = row0 + row;
            size_t ab = ((size_t)(ar / arpb) * absr + aoff + (ar % arpb)) * (size_t)K + kk + scol;
            us4 ap;
            if (ABF16) {
                ap = *(const us4*)((const unsigned short*)Av + ab);
            } else {
                float4 av = *(const float4*)((const float*)Av + ab);
                ap.x = f2bf(av.x); ap.y = f2bf(av.y); ap.z = f2bf(av.z); ap.w = f2bf(av.w);
            }
            *(us4*)&Asl[row][((sslot ^ (row & 7)) << 3) + (shalf << 2)] = ap;
            us4 bv = *(const us4*)(Bt + (size_t)(col0 + row) * bstr + kk + scol);
            *(us4*)&Bsl[row][((sslot ^ (row & 7)) << 3) + (shalf << 2)] = bv;
        }
        __syncthreads();
        #pragma unroll
        for (int k2 = 0; k2 < 2; ++k2) {
            short8 af[2], bfr[2];
            #pragma unroll
            for (int m = 0; m < 2; ++m) {
                int rowA = wr * 32 + m * 16 + lrow;
                af[m] = *(short8*)&Asl[rowA][((k2 * 4 + lk) ^ (rowA & 7)) << 3];
                int rowB = wc * 32 + m * 16 + lrow;
                bfr[m] = *(short8*)&Bsl[rowB][((k2 * 4 + lk) ^ (rowB & 7)) << 3];
            }
            #pragma unroll
            for (int m = 0; m < 2; ++m)
                #pragma unroll
                for (int n = 0; n < 2; ++n)
                    acc[m][n] = __builtin_amdgcn_mfma_f32_16x16x32_bf16(af[m], bfr[n], acc[m][n], 0, 0, 0);
        }
        __syncthreads();
    }
    #pragma unroll
    for (int m = 0; m < 2; ++m) {
        #pragma unroll
        for (int n = 0; n < 2; ++n) {
            int col = col0 + wc * 32 + n * 16 + lrow;
            #pragma unroll
            for (int j = 0; j < 4; ++j) {
                int r = row0 + wr * 32 + m * 16 + lk * 4 + j;
                size_t cp = ((size_t)(r / crpb) * cbsr + coff + (r % crpb)) * (size_t)N + col;
                float o = acc[m][n][j];
                if (BIAS)   o += bias[col];
                if (DOGELU) o = gelu_f(o);
                if (RES)    o += Res[cp];
                if (CBF16) ((unsigned short*)Cv)[cp] = f2bf(o);
                else       ((float*)Cv)[cp] = o;
            }
        }
    }
}

template<int BIAS, int DOGELU, int RES, int ABF16, int CBF16>
__global__ __launch_bounds__(256) void mgemm_k(
    const void* __restrict__ Av, const unsigned short* __restrict__ Bt,
    const float* __restrict__ bias, const float* __restrict__ Res,
    void* __restrict__ Cv, int M, int N, int K, int bstr,
    int arpb, int absr, int aoff, int crpb, int cbsr, int coff)
{
    mgemm_body<BIAS, DOGELU, RES, ABF16, CBF16>(
        Av, Bt, bias, Res, Cv, N, K, bstr, arpb, absr, aoff, crpb, cbsr, coff,
        blockIdx.x * 64, blockIdx.y * 64);
}

// ---------------- merged KVG (x<8) + GKVQ (x>=8, y==0) projections ----------------
__global__ __launch_bounds__(256) void kvg_pair_k(
    const float* __restrict__ outp, const float* __restrict__ GQ,
    const unsigned short* __restrict__ wt_gakv,
    unsigned short* __restrict__ KVGb, unsigned short* __restrict__ GKVQb)
{
    int x = blockIdx.x, y = blockIdx.y;
    if (x < 8) {
        mgemm_body<0,0,0,0,1>(outp, wt_gakv, nullptr, nullptr, KVGb,
            512, 256, 256, LS, ROWS_B, 0, 4096, 4096, 0, x * 64, y * 64);
    } else {
        if (y != 0) return;
        mgemm_body<0,0,0,0,1>(GQ, wt_gakv, nullptr, nullptr, GKVQb,
            768, 256, 256, 64, 64, 0, 64, 64, 0, (x - 8) * 64, 0);
    }
}

// ---------------- fused spatial attention (K+V prefetched together) ----------------
__global__ __launch_bounds__(256) void attn_sp_k(
    const unsigned short* __restrict__ QKV, const unsigned short* __restrict__ KVGLb,
    const int* __restrict__ idx, const float* __restrict__ rpe,
    const float* __restrict__ srpe, const float* __restrict__ dist,
    const float* __restrict__ lsig, const float* __restrict__ gbias,
    unsigned short* __restrict__ ORb)
{
    __shared__ float s_rpe[17 * 32];
    __shared__ float s_sc[NCTX * 8];
    __shared__ float s_red[32 * 64];
    __shared__ float s_d[16];
    __shared__ int   s_row[17];
    int t = threadIdx.x;
    int r = blockIdx.x;
    int b = r >> 11;
    int w = t >> 6, lane = t & 63;
    int h = lane >> 3, dg = lane & 7;

    if (t < 32) s_rpe[t] = srpe[(size_t)r * 32 + t];
    for (int i = t; i < 512; i += 256) s_rpe[32 + i] = rpe[(size_t)r * 512 + i];
    if (t < 16) {
        s_row[t + 1] = (b << 11) + idx[r * 16 + t];
        s_d[t] = dist[(size_t)r * 16 + t];
    }
    if (t == 16) s_row[0] = r;

    size_t qb = (size_t)r * QSTR + lane * 4;
    float4 q4  = bf2f4(*(const us4*)(QKV + qb));
    float4 qw4 = bf2f4(*(const us4*)(QKV + qb + 768));
    float inv2s = 1.0f / (2.0f * __expf(2.0f * lsig[h]));
    float gb = gbias[0];
    __syncthreads();

    // prefetch BOTH K and V rows for this wave's 5 local contexts (10 loads in flight)
    us4 kreg[5], vreg[5];
    #pragma unroll
    for (int i = 0; i < 5; ++i) {
        int c = w + 4 * i;
        if (c < 17) {
            const unsigned short* rowp = QKV + (size_t)s_row[c] * QSTR + lane * 4;
            kreg[i] = *(const us4*)(rowp + 256);
            vreg[i] = *(const us4*)(rowp + 512);
        }
    }
    float sc_loc[5];
    #pragma unroll
    for (int i = 0; i < 5; ++i) {
        int c = w + 4 * i;
        if (c < 17) {
            float4 k4 = bf2f4(kreg[i]);
            float4 rv4 = *(const float4*)&s_rpe[c * 32 + dg * 4];
            float part = dot4(q4, k4) + dot4(rv4, qw4);
            part += __shfl_xor(part, 1);
            part += __shfl_xor(part, 2);
            part += __shfl_xor(part, 4);
            float bia = (c == 0) ? 0.0f : -s_d[c - 1] * s_d[c - 1] * inv2s;
            float sval = part * SCALE + bia;
            if (dg == 0) s_sc[c * 8 + h] = sval;
            sc_loc[i] = sval;
        }
    }
    float sc_glob[8];
    #pragma unroll
    for (int i = 0; i < 8; ++i) {
        int gi = w + 4 * i;
        float sval = bf2f(QKV[(size_t)r * QSTR + 1024 + (((size_t)b * 32 + gi) << 3) + h]) * SCALE + gb;
        if (dg == 0) s_sc[(17 + gi) * 8 + h] = sval;
        sc_glob[i] = sval;
    }
    __syncthreads();

    float vals[7];
    float lm = -3.0e38f;
    #pragma unroll
    for (int i = 0; i < 7; ++i) {
        int cc = dg + 8 * i;
        if (cc < NCTX) { float v = s_sc[cc * 8 + h]; vals[i] = v; lm = fmaxf(lm, v); }
    }
    lm = fmaxf(lm, __shfl_xor(lm, 1));
    lm = fmaxf(lm, __shfl_xor(lm, 2));
    lm = fmaxf(lm, __shfl_xor(lm, 4));
    float ls = 0.0f;
    #pragma unroll
    for (int i = 0; i < 7; ++i) {
        int cc = dg + 8 * i;
        if (cc < NCTX) ls += __expf(vals[i] - lm);
    }
    ls += __shfl_xor(ls, 1);
    ls += __shfl_xor(ls, 2);
    ls += __shfl_xor(ls, 4);
    float inv = 1.0f / ls;

    float4 acc4 = (float4){0, 0, 0, 0}, racc4 = (float4){0, 0, 0, 0};
    #pragma unroll
    for (int i = 0; i < 5; ++i) {
        int c = w + 4 * i;
        if (c < 17) {
            float p = __expf(sc_loc[i] - lm);
            float4 v4 = bf2f4(vreg[i]);
            float4 rv4 = *(const float4*)&s_rpe[c * 32 + dg * 4];
            racc4.x += p * rv4.x; racc4.y += p * rv4.y;
            racc4.z += p * rv4.z; racc4.w += p * rv4.w;
            acc4.x += p * v4.x; acc4.y += p * v4.y;
            acc4.z += p * v4.z; acc4.w += p * v4.w;
        }
    }
    #pragma unroll
    for (int i = 0; i < 8; ++i) {
        int gi = w + 4 * i;
        float p = __expf(sc_glob[i] - lm);
        float4 v4 = bf2f4(*(const us4*)(KVGLb + ((size_t)(b * NG + gi)) * 512 + 256 + lane * 4));
        acc4.x += p * v4.x; acc4.y += p * v4.y;
        acc4.z += p * v4.z; acc4.w += p * v4.w;
    }

    s_red[(w * 8 + 0) * 64 + lane] = acc4.x;
    s_red[(w * 8 + 1) * 64 + lane] = acc4.y;
    s_red[(w * 8 + 2) * 64 + lane] = acc4.z;
    s_red[(w * 8 + 3) * 64 + lane] = acc4.w;
    s_red[(w * 8 + 4) * 64 + lane] = racc4.x;
    s_red[(w * 8 + 5) * 64 + lane] = racc4.y;
    s_red[(w * 8 + 6) * 64 + lane] = racc4.z;
    s_red[(w * 8 + 7) * 64 + lane] = racc4.w;
    __syncthreads();
    {
        int j = w;
        float a = 0.0f, rr = 0.0f;
        #pragma unroll
        for (int ww = 0; ww < 4; ++ww) {
            a  += s_red[(ww * 8 + j) * 64 + lane];
            rr += s_red[(ww * 8 + 4 + j) * 64 + lane];
        }
        int e = h * 32 + dg * 4 + j;
        ORb[(size_t)r * 512 + e]       = f2bf(a * inv);
        ORb[(size_t)r * 512 + 256 + e] = f2bf(rr * inv);
    }
}

// ---------------- global attention: scores via MFMA ----------------
__global__ __launch_bounds__(256) void ga_scores_k(
    const unsigned short* __restrict__ GKVQ, const unsigned short* __restrict__ KVG,
    float* __restrict__ A2)
{
    int t = threadIdx.x;
    int bh = blockIdx.x;
    int b = bh >> 3, h = bh & 7;
    int w = t >> 6, lane = t & 63;
    int ct = blockIdx.y * 4 + w;
    if (ct >= 130) return;
    int lr = lane & 15, lq = lane >> 4;

    short8 aq0 = *(const short8*)(GKVQ + ((size_t)(b * 32 + lr)) * 768 + 512 + h * 32 + lq * 8);
    short8 aq1 = *(const short8*)(GKVQ + ((size_t)(b * 32 + 16 + lr)) * 768 + 512 + h * 32 + lq * 8);
    int c = ct * 16 + lr;
    const unsigned short* kr = (c < LS)
        ? KVG + ((size_t)(b * LS + c)) * 512 + h * 32 + lq * 8
        : GKVQ + ((size_t)(b * NG + (c - LS))) * 768 + h * 32 + lq * 8;
    short8 bk = *(const short8*)kr;

    f32x4 acc0 = (f32x4){0, 0, 0, 0}, acc1 = (f32x4){0, 0, 0, 0};
    acc0 = __builtin_amdgcn_mfma_f32_16x16x32_bf16(aq0, bk, acc0, 0, 0, 0);
    acc1 = __builtin_amdgcn_mfma_f32_16x16x32_bf16(aq1, bk, acc1, 0, 0, 0);

    float* arow = A2 + ((size_t)(b * NH + h) * NG) * ROWS_B + ct * 16 + lr;
    #pragma unroll
    for (int j = 0; j < 4; ++j) {
        arow[(size_t)(lq * 4 + j) * ROWS_B]        = acc0[j] * SCALE;
        arow[(size_t)(16 + lq * 4 + j) * ROWS_B]   = acc1[j] * SCALE;
    }
}

// ---------------- global attention: softmax stats (no normalize pass) ----------------
// Writes exp(s - M) into A2 and 1/sum into rinv[row]; ga_wv applies the scale.
__global__ __launch_bounds__(256) void ga_softmax_k(float* __restrict__ A2, float* __restrict__ rinv)
{
    __shared__ float red[8];
    int t = threadIdx.x;
    float* row = A2 + (size_t)blockIdx.x * ROWS_B;
    float lm = -1e30f;
    for (int i = t; i < ROWS_B; i += 256) lm = fmaxf(lm, row[i]);
    #pragma unroll
    for (int m = 32; m >= 1; m >>= 1) lm = fmaxf(lm, __shfl_xor(lm, m));
    if ((t & 63) == 0) red[t >> 6] = lm;
    __syncthreads();
    float M = fmaxf(fmaxf(red[0], red[1]), fmaxf(red[2], red[3]));
    float ls = 0.0f;
    for (int i = t; i < ROWS_B; i += 256) {
        float e = __expf(row[i] - M);
        row[i] = e;
        ls += e;
    }
    #pragma unroll
    for (int m = 32; m >= 1; m >>= 1) ls += __shfl_xor(ls, m);
    if ((t & 63) == 0) red[4 + (t >> 6)] = ls;
    __syncthreads();
    if (t == 0) rinv[blockIdx.x] = 1.0f / (red[4] + red[5] + red[6] + red[7]);
}

// ---------------- global attention: weighted V (32-way split-K, bf16, applies rinv) ----
__global__ __launch_bounds__(256) void ga_wv_k(
    const float* __restrict__ A2, const float* __restrict__ rinv,
    const unsigned short* __restrict__ GKVQ,
    const unsigned short* __restrict__ KVG, float* __restrict__ OGP)
{
    __shared__ float s_acc[8][256];
    int t = threadIdx.x;
    int bg = blockIdx.x;       // b*32+g
    int s = blockIdx.y;        // 0..31
    int b = bg >> 5, g = bg & 31;
    int tt = t & 31, sub = t >> 5;
    int h = tt >> 2;
    const float* w = A2 + ((size_t)(b * NH + h) * NG + g) * ROWS_B;
    int c0 = s * 65, cend = c0 + 65;
    float acc[8] = {};
    for (int c = c0 + sub; c < cend; c += 8) {
        float p = w[c];
        const unsigned short* vr = (c < LS)
            ? KVG + ((size_t)(b * LS + c)) * 512 + 256 + tt * 8
            : GKVQ + ((size_t)(b * NG + (c - LS))) * 768 + 256 + tt * 8;
        us4 v0 = *(const us4*)vr;
        us4 v1 = *(const us4*)(vr + 4);
        acc[0] += p * bf2f(v0.x); acc[1] += p * bf2f(v0.y);
        acc[2] += p * bf2f(v0.z); acc[3] += p * bf2f(v0.w);
        acc[4] += p * bf2f(v1.x); acc[5] += p * bf2f(v1.y);
        acc[6] += p * bf2f(v1.z); acc[7] += p * bf2f(v1.w);
    }
    #pragma unroll
    for (int j = 0; j < 8; ++j) s_acc[sub][tt * 8 + j] = acc[j];
    __syncthreads();
    float o = 0.0f;
    #pragma unroll
    for (int ss = 0; ss < 8; ++ss) o += s_acc[ss][t];
    o *= rinv[((size_t)b * NH + (t >> 5)) * NG + g];
    OGP[((size_t)bg * 32 + s) * 256 + t] = o;
}

// ---------------- glob tail, 4 blocks per row ----------------
__global__ __launch_bounds__(1024) void glob_tail_k(
    const float* __restrict__ OGP, const float* __restrict__ latents,
    const float* __restrict__ ga_wo, const float* __restrict__ ga_bo,
    const float* __restrict__ ln4g, const float* __restrict__ ln4b,
    const float* __restrict__ w1, const float* __restrict__ b1,
    const float* __restrict__ w2, const float* __restrict__ b2,
    float* __restrict__ GTP)
{
    __shared__ float s_part[4][256];
    __shared__ float s_og[256];
    __shared__ float s_y[256];
    __shared__ float s_h1[256];
    __shared__ float red[16];
    int bg = blockIdx.x, q = blockIdx.y, t = threadIdx.x;
    int tt = t & 255, grp = t >> 8;

    float og = 0.0f;
    #pragma unroll
    for (int s = 0; s < 8; ++s)
        og += OGP[((size_t)bg * 32 + grp * 8 + s) * 256 + tt];
    s_part[grp][tt] = og;
    __syncthreads();
    if (grp == 0) s_og[tt] = s_part[0][tt] + s_part[1][tt] + s_part[2][tt] + s_part[3][tt];
    __syncthreads();

    float x = 0.0f;
    {
        int k0 = grp * 64;
        #pragma unroll 16
        for (int k = k0; k < k0 + 64; ++k) x += s_og[k] * ga_wo[(size_t)k * 256 + tt];
    }
    s_part[grp][tt] = x;
    __syncthreads();
    int b = bg >> 5;
    size_t row = (size_t)b * ROWS_B + LS + (bg & 31);
    float res = latents[row * 256 + tt]
              + s_part[0][tt] + s_part[1][tt] + s_part[2][tt] + s_part[3][tt] + ga_bo[tt];

    float a = res, b2s = res * res;
    #pragma unroll
    for (int m = 32; m >= 1; m >>= 1) { a += __shfl_xor(a, m); b2s += __shfl_xor(b2s, m); }
    if ((t & 63) == 0 && t < 256) { red[t >> 6] = a; red[8 + (t >> 6)] = b2s; }
    __syncthreads();
    float mean = (red[0] + red[1] + red[2] + red[3]) * (1.0f / 256.0f);
    float var  = (red[8] + red[9] + red[10] + red[11]) * (1.0f / 256.0f) - mean * mean;
    float y = (res - mean) * rsqrtf(var + 1e-5f) * ln4g[tt] + ln4b[tt];
    if (grp == 0) s_y[tt] = y;
    __syncthreads();

    float h1p = 0.0f;
    {
        int k0 = grp * 64;
        #pragma unroll 16
        for (int k = k0; k < k0 + 64; ++k) h1p += s_y[k] * w1[(size_t)k * 1024 + q * 256 + tt];
    }
    s_part[grp][tt] = h1p;
    __syncthreads();
    if (grp == 0)
        s_h1[tt] = gelu_f(b1[q * 256 + tt]
                 + s_part[0][tt] + s_part[1][tt] + s_part[2][tt] + s_part[3][tt]);
    __syncthreads();

    float o = 0.0f;
    {
        int j0 = grp * 64;
        #pragma unroll 16
        for (int j = j0; j < j0 + 64; ++j) o += s_h1[j] * w2[(size_t)(q * 256 + j) * 256 + tt];
    }
    s_part[grp][tt] = o;
    __syncthreads();
    if (grp == 0) {
        float v = s_part[0][tt] + s_part[1][tt] + s_part[2][tt] + s_part[3][tt];
        if (q == 0) v += res + b2[tt];
        GTP[((size_t)bg * 4 + q) * 256 + tt] = v;
    }
}

__global__ __launch_bounds__(256) void glob_fin_k(
    const float* __restrict__ GTP, float* __restrict__ out)
{
    int bg = blockIdx.x, t = threadIdx.x;
    int b = bg >> 5;
    size_t row = (size_t)b * ROWS_B + LS + (bg & 31);
    float v = GTP[((size_t)bg * 4 + 0) * 256 + t] + GTP[((size_t)bg * 4 + 1) * 256 + t]
            + GTP[((size_t)bg * 4 + 2) * 256 + t] + GTP[((size_t)bg * 4 + 3) * 256 + t];
    out[row * 256 + t] = v;
}

// ---------------- launch ----------------
extern "C" void kernel_launch(void* const* d_in, const int* in_sizes, int n_in,
                              void* d_out, int out_size, void* d_ws, size_t ws_size,
                              hipStream_t stream)
{
    const float* latents = (const float*)d_in[0];
    const int*   idx     = (const int*)d_in[1];
    const float* rpe     = (const float*)d_in[2];
    const float* srpe    = (const float*)d_in[3];
    const float* dist    = (const float*)d_in[4];
    const float* sa_wq   = (const float*)d_in[6];
    const float* sa_wk   = (const float*)d_in[7];
    const float* sa_wv   = (const float*)d_in[8];
    const float* sa_wo   = (const float*)d_in[9];
    const float* sa_bo   = (const float*)d_in[10];
    const float* lsig    = (const float*)d_in[11];
    const float* gbias   = (const float*)d_in[12];
    const float* ln1g    = (const float*)d_in[13];
    const float* ln1b    = (const float*)d_in[14];
    const float* ln2g    = (const float*)d_in[15];
    const float* ln2b    = (const float*)d_in[16];
    const float* sff_w1  = (const float*)d_in[17];
    const float* sff_b1  = (const float*)d_in[18];
    const float* sff_w2  = (const float*)d_in[19];
    const float* sff_b2  = (const float*)d_in[20];
    const float* ga_wq   = (const float*)d_in[21];
    const float* ga_wk   = (const float*)d_in[22];
    const float* ga_wv   = (const float*)d_in[23];
    const float* ga_wo   = (const float*)d_in[24];
    const float* ga_bo   = (const float*)d_in[25];
    const float* ln3g    = (const float*)d_in[27];
    const float* ln3b    = (const float*)d_in[28];
    const float* ln4g    = (const float*)d_in[29];
    const float* ln4b    = (const float*)d_in[30];
    const float* gff_w1  = (const float*)d_in[31];
    const float* gff_b1  = (const float*)d_in[32];
    const float* gff_w2  = (const float*)d_in[33];
    const float* gff_b2  = (const float*)d_in[34];
    float* out = (float*)d_out;

    const size_t SZ = (size_t)4096 * 256;
    float* ws = (float*)d_ws;
    unsigned short* Xb = (unsigned short*)ws;              // bf16 [4096][256]
    unsigned short* QKV2b = (unsigned short*)(ws + SZ);    // [SZ,4SZ) bf16 [4096][1536]
    unsigned short* H1b  = QKV2b;
    unsigned short* KVGb = QKV2b;
    unsigned short* ORb  = (unsigned short*)(ws + 4 * SZ); // bf16 [4096][512]
    float* A2  = ws + 5 * SZ;
    float* OGP = A2 + (size_t)2 * NH * NG * ROWS_B;        // [64*32][256]
    float* GTP = OGP + (size_t)64 * 32 * 256;              // [64*4][256]
    float* RINV = GTP + (size_t)64 * 4 * 256;              // [512]
    unsigned short* wt = (unsigned short*)(ws + 7 * SZ);
    unsigned short* wt_qkvw = wt;                          // [1024][256]
    unsigned short* wgs_w   = wt + 262144;                 // [512][256]
    unsigned short* wt_ff1  = wt + 393216;                 // [1024][256]
    unsigned short* wt_ff2  = wt + 655360;                 // [256][1024]
    unsigned short* wt_gakv = wt + 917504;                 // [768][256]
    unsigned short* wt_wo2  = wt + 1114112;                // [256][512]
    float* smalls = ws + 8 * SZ;
    unsigned short* KVGLb = (unsigned short*)smalls;       // bf16 [64][512]
    float* GQ = smalls + 16384;                            // f32 [64][256]
    unsigned short* GKVQb = (unsigned short*)(GQ + 16384); // bf16 [64][768]

    dim3 blk(256);

    WTab tab;
    tab.e[0] = { sa_wq,  wt_qkvw,           256,  256,   0 };
    tab.e[1] = { sa_wk,  wt_qkvw + 65536,   256,  256,  16 };
    tab.e[2] = { sa_wv,  wt_qkvw + 131072,  256,  256,  32 };
    tab.e[3] = { sff_w1, wt_ff1,            256, 1024,  48 };
    tab.e[4] = { sff_w2, wt_ff2,           1024,  256, 112 };
    tab.e[5] = { ga_wk,  wt_gakv,           256,  256, 176 };
    tab.e[6] = { ga_wv,  wt_gakv + 65536,   256,  256, 192 };
    tab.e[7] = { ga_wq,  wt_gakv + 131072,  256,  256, 208 };
    tab.e[8] = { sa_wq,  wt_qkvw,           256,  256, 1 << 30 };

    // merged prep: wspecial + wconv + ln1/ln3 (X bf16)
    wprep_k<<<dim3(4896), blk, 0, stream>>>(tab, sa_wq, sa_wk, sa_wv, sa_wo,
                                            wt_qkvw, wt_wo2, latents,
                                            ln1g, ln1b, ln3g, ln3b, Xb, GQ);

    // spatial-attn glob K|V (bf16), then glob-score fold weights
    mgemm_k<0,0,0,0,1><<<dim3(8,1), blk, 0, stream>>>(latents, wt_qkvw + 65536, nullptr, nullptr, KVGLb,
        64,512,256,256, 32,ROWS_B,LS, 64,64,0);
    wgs_k<<<dim3(512), blk, 0, stream>>>(wt_qkvw, KVGLb, wgs_w);

    // QKV + qw + glob-scores in ONE GEMM (N=1536, A bf16)
    mgemm_k<0,0,0,1,1><<<dim3(24,64), blk, 0, stream>>>(Xb, wt_qkvw, nullptr, nullptr, QKV2b,
        4096,QSTR,256,256, 4096,4096,0, 4096,4096,0);

    // fused spatial attention -> ORb = [O_base | R] (bf16)
    attn_sp_k<<<dim3(4096), blk, 0, stream>>>(QKV2b, KVGLb, idx, rpe, srpe, dist,
                                              lsig, gbias, ORb);

    // spatial residual: out = latents + ORb @ [Wo;Wvo] + bo
    mgemm_k<1,0,1,1,0><<<dim3(4,64), blk, 0, stream>>>(ORb, wt_wo2, sa_bo, latents, out,
        4096,256,512,512, 4096,4096,0, LS,ROWS_B,0);

    // spatial FF (X bf16)
    ln_rows_k<<<dim3(4096), blk, 0, stream>>>(out, ln2g, ln2b, Xb);
    mgemm_k<1,1,0,1,1><<<dim3(16,64), blk, 0, stream>>>(Xb, wt_ff1, sff_b1, nullptr, H1b,
        4096,1024,256,256, 4096,4096,0, 4096,4096,0);
    mgemm_k<1,0,1,1,0><<<dim3(4,64), blk, 0, stream>>>(H1b, wt_ff2, sff_b2, out, out,
        4096,256,1024,1024, 4096,4096,0, LS,ROWS_B,0);

    // merged global-attention projections
    kvg_pair_k<<<dim3(20,64), blk, 0, stream>>>(out, GQ, wt_gakv, KVGb, GKVQb);

    // global attention
    ga_scores_k<<<dim3(16, 33), blk, 0, stream>>>(GKVQb, KVGb, A2);
    ga_softmax_k<<<dim3(512), blk, 0, stream>>>(A2, RINV);
    ga_wv_k<<<dim3(64, 32), blk, 0, stream>>>(A2, RINV, GKVQb, KVGb, OGP);

    // glob tail: 4-way sliced + final combine
    glob_tail_k<<<dim3(64, 4), dim3(1024), 0, stream>>>(OGP, latents, ga_wo, ga_bo, ln4g, ln4b,
                                                        gff_w1, gff_b1, gff_w2, gff_b2, GTP);
    glob_fin_k<<<dim3(64), blk, 0, stream>>>(GTP, out);
}